// Round 9
// baseline (1674.938 us; speedup 1.0000x reference)
//
#include <hip/hip_runtime.h>
#include <hip/hip_bf16.h>

// DGCNN-style KNN classifier. B=8, N=2048, K=10.
// g_flag=1 -> bf16 inputs, 0 -> fp32 (runtime probe). Output same dtype.
// Scratch in static __device__ globals; every byte read is written earlier in
// the same launch (graph-replay safe).
//
// R8->R9: fused dist+topk into knn_fused (kills the 134MB g_D HBM round trip
// per layer: MFMA D-tile -> LDS -> per-thread sorted top-10 scan -> merge).
// w5max wave tile 16x64 -> 32x64 (loads/MFMA 0.83 -> 0.5; was TA-issue bound
// at MfmaUtil 23%).

#define NEG 0.2f
#define FMAX 3.402823466e+38f

typedef __hip_bfloat16 bf16;
typedef __attribute__((ext_vector_type(8))) short s8v;    // 8 bf16
typedef __attribute__((ext_vector_type(4))) float f32x4;  // MFMA acc

#define BB 8
#define NN 2048
#define BNTOT (BB * NN)

#define OFF_CAT ((size_t)0)
#define OFF_G (OFF_CAT + (size_t)BNTOT * 512)
#define OFF_NORMS (OFF_G + (size_t)BNTOT * 128)
#define OFF_PART (OFF_NORMS + BNTOT)
#define OFF_POOLED (OFF_PART + 8 * 1024 * 32)
#define OFF_H1 (OFF_POOLED + 8 * 1024)
#define OFF_H2 (OFF_H1 + 8 * 512)
#define WSF_TOTAL (OFF_H2 + 8 * 256)

__device__ float g_ws_f[WSF_TOTAL];          // ~43.1 MB
__device__ int g_ws_i[(size_t)BNTOT * 10];   // knn idx
__device__ int g_flag;                       // 1 = bf16 inputs, 0 = fp32
__device__ unsigned short g_hi[(size_t)BNTOT * 512];   // split-bf16 hi (frag-tiled)
__device__ unsigned short g_lo[(size_t)BNTOT * 512];
__device__ unsigned short g_whi[1024 * 512];           // split W5 (frag-tiled)
__device__ unsigned short g_wlo[1024 * 512];

__device__ __forceinline__ float ldany(const void* p, size_t i, int isb) {
  if (isb) return __bfloat162float(((const bf16*)p)[i]);
  return ((const float*)p)[i];
}

// ---------------- dtype probe ----------------
__global__ void probe_kernel(const void* pts) {
  const unsigned* w = (const unsigned*)pts;
  int cnt = 0;
  for (int i = 0; i < 256; ++i) {
    unsigned e2 = (w[i] >> 7) & 0xFF;
    cnt += (e2 >= 110 && e2 <= 135);
  }
  g_flag = (cnt > 128) ? 1 : 0;
}

// ---------------- norms ----------------
template <bool XDYN>
__global__ void norms_kernel(const void* xraw, size_t xoff, int lda, int C, int BN) {
  const int isb = g_flag;
  float* norms = g_ws_f + OFF_NORMS;
  int row = blockIdx.x * (blockDim.x >> 6) + (threadIdx.x >> 6);
  int lane = threadIdx.x & 63;
  if (row >= BN) return;
  float s = 0.f;
  for (int c = lane; c < C; c += 64) {
    float v = XDYN ? ldany(xraw, (size_t)row * lda + c, isb)
                   : g_ws_f[xoff + (size_t)row * lda + c];
    s += v * v;
  }
#pragma unroll
  for (int off = 32; off > 0; off >>= 1) s += __shfl_down(s, off, 64);
  if (lane == 0) norms[row] = s;
}

// ------- split-bf16 into MFMA-fragment-tile layout -------
// out[t*512 + quad*128 + l16*8 + j], t=(r/16)*(CPAD/32)+(k/32). csh2=log2(CPAD/32).
__global__ void split_kernel(const void* xraw, size_t xoff, int lda, int C,
                             int csh2, int dst, int total) {
  int i = blockIdx.x * blockDim.x + threadIdx.x;
  if (i >= total) return;
  const int isb = g_flag;
  int t = i >> 9, win = i & 511;
  int quad = win >> 7, l16 = (win >> 3) & 15, j = win & 7;
  int ktiles_m1 = (1 << csh2) - 1;
  int rg = t >> csh2, kt = t & ktiles_m1;
  int r = rg * 16 + l16;
  int c = kt * 32 + quad * 8 + j;
  float v = 0.f;
  if (c < C)
    v = xraw ? ldany(xraw, (size_t)r * lda + c, isb) : g_ws_f[xoff + (size_t)r * lda + c];
  bf16 h = __float2bfloat16(v);
  float hf = __bfloat162float(h);
  bf16 l = __float2bfloat16(v - hf);
  unsigned short* H = dst ? g_whi : g_hi;
  unsigned short* L = dst ? g_wlo : g_lo;
  H[i] = *(unsigned short*)&h;
  L[i] = *(unsigned short*)&l;
}

// ---------------- fused KNN: MFMA distances + top-10, no g_D ----------------
// block = 256 thr (4 waves) per (b, 64-query tile). A-frags in regs across all
// m-tiles; per tile: MFMA -> sd[q][m] LDS -> per-thread sorted top-10 insert
// (thread (lane=query, wave=m-slice)); final 4-way lexicographic merge.
template <int CPAD>
__global__ __launch_bounds__(256) void knn_fused(int N) {
  constexpr int KT = CPAD >> 5;
  __shared__ float sd[64][67];
  __shared__ float mval[64][4][10];
  __shared__ int midx[64][4][10];
  const int tid = threadIdx.x;
  const int wave = tid >> 6, lane = tid & 63;
  const int quad = lane >> 4, l16 = lane & 15;
  const int b = blockIdx.y;
  const int q0 = blockIdx.x * 64;
  const size_t rowb = (size_t)b * N;
  const float* norms = g_ws_f + OFF_NORMS;

  // A fragments held in registers (queries q0 + wave*16 + l16)
  const int arg = (int)((rowb + q0) >> 4) + wave;
  s8v ah[KT], al[KT];
#pragma unroll
  for (int kt = 0; kt < KT; ++kt) {
    const size_t abase = ((size_t)arg * KT + kt) * 512 + lane * 8;
    ah[kt] = *(const s8v*)(g_hi + abase);
    al[kt] = *(const s8v*)(g_lo + abase);
  }

  float bv[10]; int bi[10];
#pragma unroll
  for (int i = 0; i < 10; ++i) { bv[i] = FMAX; bi[i] = 0x7fffffff; }
  const int selfn = q0 + lane;  // this thread maintains query q0+lane

  for (int m0 = 0; m0 < N; m0 += 64) {
    f32x4 acc[4];
#pragma unroll
    for (int s = 0; s < 4; ++s) acc[s] = (f32x4){0.f, 0.f, 0.f, 0.f};
    const int brg0 = (int)((rowb + m0) >> 4);
#pragma unroll
    for (int kt = 0; kt < KT; ++kt) {
#pragma unroll
      for (int s = 0; s < 4; ++s) {
        const size_t bbase = ((size_t)(brg0 + s) * KT + kt) * 512 + lane * 8;
        s8v bh = *(const s8v*)(g_hi + bbase);
        s8v bl = *(const s8v*)(g_lo + bbase);
        acc[s] = __builtin_amdgcn_mfma_f32_16x16x32_bf16(ah[kt], bh, acc[s], 0, 0, 0);
        acc[s] = __builtin_amdgcn_mfma_f32_16x16x32_bf16(ah[kt], bl, acc[s], 0, 0, 0);
        acc[s] = __builtin_amdgcn_mfma_f32_16x16x32_bf16(al[kt], bh, acc[s], 0, 0, 0);
      }
    }
    __syncthreads();  // previous tile's scan is done before overwrite
#pragma unroll
    for (int s = 0; s < 4; ++s) {
      int ml = s * 16 + l16;
      float nm = norms[rowb + m0 + ml];
#pragma unroll
      for (int r = 0; r < 4; ++r)
        sd[wave * 16 + quad * 4 + r][ml] = nm - 2.f * acc[s][r];
    }
    __syncthreads();
    // scan: thread (query=lane, slice=wave) consumes 16 candidates
    const int mbase = m0 + wave * 16;
#pragma unroll
    for (int jj = 0; jj < 16; ++jj) {
      int m = mbase + jj;
      float d = sd[lane][wave * 16 + jj];
      if (m == selfn) continue;
      bool ins = (d < bv[9]) || (d == bv[9] && m < bi[9]);
      if (ins) {
        bool prev = true;
#pragma unroll
        for (int s2 = 9; s2 >= 1; --s2) {
          bool sh = (d < bv[s2 - 1]) || (d == bv[s2 - 1] && m < bi[s2 - 1]);
          float nv = sh ? bv[s2 - 1] : (prev ? d : bv[s2]);
          int ni = sh ? bi[s2 - 1] : (prev ? m : bi[s2]);
          bv[s2] = nv; bi[s2] = ni; prev = sh;
        }
        if (prev) { bv[0] = d; bi[0] = m; }
      }
    }
  }
  // merge 4 partial lists per query
#pragma unroll
  for (int i = 0; i < 10; ++i) { mval[lane][wave][i] = bv[i]; midx[lane][wave][i] = bi[i]; }
  __syncthreads();
  if (tid < 64) {
    int q = tid;
    int p0 = 0, p1 = 0, p2 = 0, p3 = 0;
    int* ob = g_ws_i + (rowb + q0 + q) * 10;
    for (int cnt = 0; cnt < 10; ++cnt) {
      float d0 = mval[q][0][p0]; int i0 = midx[q][0][p0];
      float d1 = mval[q][1][p1]; int i1 = midx[q][1][p1];
      float d2 = mval[q][2][p2]; int i2 = midx[q][2][p2];
      float d3 = mval[q][3][p3]; int i3 = midx[q][3][p3];
      float bd = d0; int bx = i0; int bp = 0;
      if (d1 < bd || (d1 == bd && i1 < bx)) { bd = d1; bx = i1; bp = 1; }
      if (d2 < bd || (d2 == bd && i2 < bx)) { bd = d2; bx = i2; bp = 2; }
      if (d3 < bd || (d3 == bd && i3 < bx)) { bd = d3; bx = i3; bp = 3; }
      if (bp == 0) ++p0; else if (bp == 1) ++p1; else if (bp == 2) ++p2; else ++p3;
      ob[cnt] = bx;
    }
  }
}

// ---------------- G[z][BN][64] = X @ W_half[o_base:+64]^T ----------------
template <bool XDYN, int C>
__global__ __launch_bounds__(256) void gmat64_kernel(const void* xraw, size_t xoff,
                                                     int lda, const void* W,
                                                     int o_base, int BN) {
  const int isb = g_flag;
  constexpr int CC = (C <= 4) ? 4 : 64;
  constexpr int NCH = (C + CC - 1) / CC;
  __shared__ __align__(16) float at[CC][68];
  __shared__ __align__(16) float wt[CC][68];
  const int tid = threadIdx.x;
  const int ty = tid >> 4, tx = tid & 15;
  const int r0 = blockIdx.x * 64;
  const int z = blockIdx.z;
  float* Gz = g_ws_f + OFF_G + (size_t)z * BN * 64;
  float acc[4][4];
#pragma unroll
  for (int i = 0; i < 4; ++i)
#pragma unroll
    for (int j = 0; j < 4; ++j) acc[i][j] = 0.f;

  for (int ch = 0; ch < NCH; ++ch) {
    int c0 = ch * CC;
    for (int i = tid; i < 64 * CC; i += 256) {
      int r = i / CC, c = i % CC; int cg = c0 + c;
      size_t gi = (size_t)(r0 + r) * lda + cg;
      at[c][r] = (cg < C) ? (XDYN ? ldany(xraw, gi, isb) : g_ws_f[xoff + gi]) : 0.f;
    }
    for (int i = tid; i < 64 * CC; i += 256) {
      int r = i / CC, c = i % CC; int cg = c0 + c;
      size_t wi = (size_t)(o_base + r) * (2 * C) + (size_t)z * C + cg;
      wt[c][r] = (cg < C) ? ldany(W, wi, isb) : 0.f;
    }
    __syncthreads();
#pragma unroll 8
    for (int c = 0; c < CC; ++c) {
      const float4 a4 = *(const float4*)&at[c][4 * ty];
      const float4 w4 = *(const float4*)&wt[c][4 * tx];
      acc[0][0] += a4.x * w4.x; acc[0][1] += a4.x * w4.y; acc[0][2] += a4.x * w4.z; acc[0][3] += a4.x * w4.w;
      acc[1][0] += a4.y * w4.x; acc[1][1] += a4.y * w4.y; acc[1][2] += a4.y * w4.z; acc[1][3] += a4.y * w4.w;
      acc[2][0] += a4.z * w4.x; acc[2][1] += a4.z * w4.y; acc[2][2] += a4.z * w4.z; acc[2][3] += a4.z * w4.w;
      acc[3][0] += a4.w * w4.x; acc[3][1] += a4.w * w4.y; acc[3][2] += a4.w * w4.z; acc[3][3] += a4.w * w4.w;
    }
    __syncthreads();
  }
#pragma unroll
  for (int i = 0; i < 4; ++i)
#pragma unroll
    for (int j = 0; j < 4; ++j)
      Gz[(size_t)(r0 + 4 * ty + i) * 64 + 4 * tx + j] = acc[i][j];
}

// ---------------- edge-conv epilogue (64-out chunk) ----------------
__global__ void edge_epi64(const void* s, const void* t, int coff,
                           size_t outoff, int BN, int N) {
  const int isb = g_flag;
  int tid = threadIdx.x;
  int p = tid >> 6, o = tid & 63;
  int row = blockIdx.x * 4 + p;
  const float* G1 = g_ws_f + OFF_G;
  const float* G2 = G1 + (size_t)BN * 64;
  float* out = g_ws_f + outoff;
  int b = row / N;
  const int* id = g_ws_i + (size_t)row * 10;
  float g1n = G1[(size_t)row * 64 + o];
  float base = G2[(size_t)row * 64 + o] - g1n;
  float sv = ldany(s, coff + o, isb), tv = ldany(t, coff + o, isb);
  float mx = -FMAX;
#pragma unroll
  for (int k = 0; k < 10; ++k) {
    int m = id[k];
    m = (m < 0) ? 0 : ((m >= N) ? N - 1 : m);
    float h = sv * (G1[((size_t)b * N + m) * 64 + o] + base) + tv;
    h = (h >= 0.f) ? h : NEG * h;
    mx = fmaxf(mx, h);
  }
  out[(size_t)row * 512 + o] = mx;
}

// ------- W5 MFMA + max over n; wave tile 32n x 64o (s5>0: affine after max) ----
__global__ __launch_bounds__(256) void w5max_mfma(const void* s5, const void* t5, int N) {
  const int tid = threadIdx.x;
  const int wave = tid >> 6, lane = tid & 63;
  const int quad = lane >> 4, l16 = lane & 15;
  const int b = blockIdx.z;
  const int o0 = blockIdx.y * 64, n0 = blockIdx.x * 128;
  f32x4 acc[2][4];
#pragma unroll
  for (int a = 0; a < 2; ++a)
#pragma unroll
    for (int s = 0; s < 4; ++s) acc[a][s] = (f32x4){0.f, 0.f, 0.f, 0.f};

  const int arg0 = (int)(((size_t)b * N + n0) >> 4) + wave * 2;  // 2 row-groups/wave
  const int wrg0 = o0 >> 4;
#pragma unroll 2
  for (int kt = 0; kt < 16; ++kt) {
    s8v ah[2], al[2];
#pragma unroll
    for (int a = 0; a < 2; ++a) {
      const size_t abase = ((size_t)(arg0 + a) * 16 + kt) * 512 + lane * 8;
      ah[a] = *(const s8v*)(g_hi + abase);
      al[a] = *(const s8v*)(g_lo + abase);
    }
#pragma unroll
    for (int s = 0; s < 4; ++s) {
      const size_t bbase = ((size_t)(wrg0 + s) * 16 + kt) * 512 + lane * 8;
      s8v bh = *(const s8v*)(g_whi + bbase);
      s8v bl = *(const s8v*)(g_wlo + bbase);
#pragma unroll
      for (int a = 0; a < 2; ++a) {
        acc[a][s] = __builtin_amdgcn_mfma_f32_16x16x32_bf16(ah[a], bh, acc[a][s], 0, 0, 0);
        acc[a][s] = __builtin_amdgcn_mfma_f32_16x16x32_bf16(ah[a], bl, acc[a][s], 0, 0, 0);
        acc[a][s] = __builtin_amdgcn_mfma_f32_16x16x32_bf16(al[a], bh, acc[a][s], 0, 0, 0);
      }
    }
  }
  __shared__ float red[4][64];
  const int isb = g_flag;
#pragma unroll
  for (int s = 0; s < 4; ++s) {
    float m4 = -FMAX;
#pragma unroll
    for (int a = 0; a < 2; ++a)
#pragma unroll
      for (int r = 0; r < 4; ++r) m4 = fmaxf(m4, acc[a][s][r]);
#pragma unroll
    for (int off = 16; off < 64; off <<= 1) m4 = fmaxf(m4, __shfl_down(m4, off, 64));
    if (quad == 0) red[wave][s * 16 + l16] = m4;
  }
  __syncthreads();
  if (tid < 64) {
    float m = fmaxf(fmaxf(red[0][tid], red[1][tid]), fmaxf(red[2][tid], red[3][tid]));
    int o = o0 + tid;
    float sv = ldany(s5, o, isb), tv = ldany(t5, o, isb);
    float h = sv * m + tv;
    h = (h >= 0.f) ? h : NEG * h;
    g_ws_f[OFF_PART + ((size_t)b * 1024 + o) * 16 + blockIdx.x] = h;
  }
}

__global__ void poolred_kernel() {
  const float* part = g_ws_f + OFF_PART;
  float* pooled = g_ws_f + OFF_POOLED;
  int i = blockIdx.x * blockDim.x + threadIdx.x;
  if (i >= 8 * 1024) return;
  const float* p = part + (size_t)i * 16;
  float m = -FMAX;
#pragma unroll
  for (int j = 0; j < 16; ++j) m = fmaxf(m, p[j]);
  pooled[i] = m;
}

// ---------------- FC: one wave per output ----------------
__global__ void fc_kernel(size_t inoff, const void* W, const void* bias,
                          const void* s, const void* t, size_t outoff, int has_out,
                          void* OUTB, int Bb, int IC, int OC, int act) {
  const int isb = g_flag;
  const float* IN = g_ws_f + inoff;
  int gw = (blockIdx.x * blockDim.x + threadIdx.x) >> 6;
  int lane = threadIdx.x & 63;
  if (gw >= Bb * OC) return;
  int b = gw / OC, o = gw % OC;
  const float* in = IN + (size_t)b * IC;
  float acc = 0.f;
  for (int c = lane; c < IC; c += 64) acc += in[c] * ldany(W, (size_t)o * IC + c, isb);
#pragma unroll
  for (int off = 32; off > 0; off >>= 1) acc += __shfl_down(acc, off, 64);
  if (lane == 0) {
    float h = acc;
    if (bias) h += ldany(bias, o, isb);
    if (s) h = h * ldany(s, o, isb) + ldany(t, o, isb);
    if (act) h = (h >= 0.f) ? h : NEG * h;
    if (has_out) g_ws_f[outoff + (size_t)b * OC + o] = h;
    if (OUTB) {
      if (isb) ((bf16*)OUTB)[(size_t)b * OC + o] = __float2bfloat16(h);
      else ((float*)OUTB)[(size_t)b * OC + o] = h;
    }
  }
}

extern "C" void kernel_launch(void* const* d_in, const int* in_sizes, int n_in,
                              void* d_out, int out_size, void* d_ws, size_t ws_size,
                              hipStream_t stream) {
  const int B = 8, N = 2048, BN = B * N;
  const void* points = d_in[0];
  const void *W1 = d_in[1], *s1 = d_in[2], *t1 = d_in[3];
  const void *W2 = d_in[4], *s2 = d_in[5], *t2 = d_in[6];
  const void *W3 = d_in[7], *s3 = d_in[8], *t3 = d_in[9];
  const void *W4 = d_in[10], *s4 = d_in[11], *t4 = d_in[12];
  const void *W5 = d_in[13], *s5 = d_in[14], *t5 = d_in[15];
  const void *Wf1 = d_in[16], *sf1 = d_in[17], *tf1 = d_in[18];
  const void *Wf2 = d_in[19], *bf2 = d_in[20], *sf2 = d_in[21], *tf2 = d_in[22];
  const void *Wf3 = d_in[23], *bf3 = d_in[24];

  probe_kernel<<<1, 1, 0, stream>>>(points);
  // split W5 (1024 rows x CPAD 512, csh2=4) once
  split_kernel<<<(1024 * 512) / 256, 256, 0, stream>>>(W5, 0, 512, 512, 4, 1, 1024 * 512);

  // ---- layer 1: points (C=3, CPAD=32, csh2=0) -> cat[:, 0:64)
  norms_kernel<true><<<BN / 4, 256, 0, stream>>>(points, 0, 3, 3, BN);
  split_kernel<<<(BN * 32) / 256, 256, 0, stream>>>(points, 0, 3, 3, 0, 0, BN * 32);
  knn_fused<32><<<dim3(N / 64, B), 256, 0, stream>>>(N);
  gmat64_kernel<true, 3><<<dim3(BN / 64, 1, 2), 256, 0, stream>>>(points, 0, 3, W1, 0, BN);
  edge_epi64<<<BN / 4, 256, 0, stream>>>(s1, t1, 0, OFF_CAT + 0, BN, N);
  // ---- layer 2: cat[:,0:64) (C=64, CPAD=64, csh2=1) -> cat[:, 64:128)
  norms_kernel<false><<<BN / 4, 256, 0, stream>>>(nullptr, OFF_CAT + 0, 512, 64, BN);
  split_kernel<<<(BN * 64) / 256, 256, 0, stream>>>(nullptr, OFF_CAT + 0, 512, 64, 1, 0, BN * 64);
  knn_fused<64><<<dim3(N / 64, B), 256, 0, stream>>>(N);
  gmat64_kernel<false, 64><<<dim3(BN / 64, 1, 2), 256, 0, stream>>>(nullptr, OFF_CAT + 0, 512, W2, 0, BN);
  edge_epi64<<<BN / 4, 256, 0, stream>>>(s2, t2, 0, OFF_CAT + 64, BN, N);
  // ---- layer 3: cat[:,64:128) (C=64) -> cat[:, 128:256)
  norms_kernel<false><<<BN / 4, 256, 0, stream>>>(nullptr, OFF_CAT + 64, 512, 64, BN);
  split_kernel<<<(BN * 64) / 256, 256, 0, stream>>>(nullptr, OFF_CAT + 64, 512, 64, 1, 0, BN * 64);
  knn_fused<64><<<dim3(N / 64, B), 256, 0, stream>>>(N);
  for (int c = 0; c < 2; ++c) {
    gmat64_kernel<false, 64><<<dim3(BN / 64, 1, 2), 256, 0, stream>>>(nullptr, OFF_CAT + 64, 512, W3, c * 64, BN);
    edge_epi64<<<BN / 4, 256, 0, stream>>>(s3, t3, c * 64, OFF_CAT + 128 + c * 64, BN, N);
  }
  // ---- layer 4: cat[:,128:256) (C=128, CPAD=128, csh2=2) -> cat[:, 256:512)
  norms_kernel<false><<<BN / 4, 256, 0, stream>>>(nullptr, OFF_CAT + 128, 512, 128, BN);
  split_kernel<<<(BN * 128) / 256, 256, 0, stream>>>(nullptr, OFF_CAT + 128, 512, 128, 2, 0, BN * 128);
  knn_fused<128><<<dim3(N / 64, B), 256, 0, stream>>>(N);
  for (int c = 0; c < 4; ++c) {
    gmat64_kernel<false, 128><<<dim3(BN / 64, 1, 2), 256, 0, stream>>>(nullptr, OFF_CAT + 128, 512, W4, c * 64, BN);
    edge_epi64<<<BN / 4, 256, 0, stream>>>(s4, t4, c * 64, OFF_CAT + 256 + c * 64, BN, N);
  }
  // ---- W5 (split full cat 512 cols, csh2=4) + global max pool
  split_kernel<<<(BN * 512) / 256, 256, 0, stream>>>(nullptr, OFF_CAT, 512, 512, 4, 0, BN * 512);
  w5max_mfma<<<dim3(16, 16, 8), 256, 0, stream>>>(s5, t5, N);
  poolred_kernel<<<32, 256, 0, stream>>>();
  // ---- FC head
  fc_kernel<<<(8 * 512 * 64) / 256, 256, 0, stream>>>(OFF_POOLED, Wf1, nullptr, sf1, tf1, OFF_H1, 1, nullptr, 8, 1024, 512, 1);
  fc_kernel<<<(8 * 256 * 64) / 256, 256, 0, stream>>>(OFF_H1, Wf2, bf2, sf2, tf2, OFF_H2, 1, nullptr, 8, 512, 256, 1);
  fc_kernel<<<6, 256, 0, stream>>>(OFF_H2, Wf3, bf3, nullptr, nullptr, 0, 0, d_out, 8, 256, 3, 0);
}

// Round 10
// 1037.530 us; speedup vs baseline: 1.6144x; 1.6144x over previous
//
#include <hip/hip_runtime.h>
#include <hip/hip_bf16.h>

// DGCNN-style KNN classifier. B=8, N=2048, K=10.
// g_flag=1 -> bf16 inputs, 0 -> fp32 (runtime probe). Output same dtype.
// Scratch in static __device__ globals; every byte read is written earlier in
// the same launch (graph-replay safe).
//
// R9->R10: knn_fused was grid-starved (256 blocks = 1/CU, occupancy 11.5%,
// 340us/layer). Candidate axis now split into P=8 partitions (2048 blocks);
// per-partition top-10 partials -> knn_merge (8-way sorted merge, 1 thr/query).
// Same lexicographic (d,idx) selection semantics.

#define NEG 0.2f
#define FMAX 3.402823466e+38f

typedef __hip_bfloat16 bf16;
typedef __attribute__((ext_vector_type(8))) short s8v;    // 8 bf16
typedef __attribute__((ext_vector_type(4))) float f32x4;  // MFMA acc

#define BB 8
#define NN 2048
#define BNTOT (BB * NN)
#define NPART 8

#define OFF_CAT ((size_t)0)
#define OFF_G (OFF_CAT + (size_t)BNTOT * 512)
#define OFF_NORMS (OFF_G + (size_t)BNTOT * 128)
#define OFF_PART (OFF_NORMS + BNTOT)
#define OFF_POOLED (OFF_PART + 8 * 1024 * 32)
#define OFF_H1 (OFF_POOLED + 8 * 1024)
#define OFF_H2 (OFF_H1 + 8 * 512)
#define WSF_TOTAL (OFF_H2 + 8 * 256)

__device__ float g_ws_f[WSF_TOTAL];          // ~43.1 MB
__device__ int g_ws_i[(size_t)BNTOT * 10];   // final knn idx
__device__ float g_pv[(size_t)BNTOT * NPART * 10];  // partial top-10 dists
__device__ int g_pi[(size_t)BNTOT * NPART * 10];    // partial top-10 idx
__device__ int g_flag;                       // 1 = bf16 inputs, 0 = fp32
__device__ unsigned short g_hi[(size_t)BNTOT * 512];   // split-bf16 hi (frag-tiled)
__device__ unsigned short g_lo[(size_t)BNTOT * 512];
__device__ unsigned short g_whi[1024 * 512];           // split W5 (frag-tiled)
__device__ unsigned short g_wlo[1024 * 512];

__device__ __forceinline__ float ldany(const void* p, size_t i, int isb) {
  if (isb) return __bfloat162float(((const bf16*)p)[i]);
  return ((const float*)p)[i];
}

// ---------------- dtype probe ----------------
__global__ void probe_kernel(const void* pts) {
  const unsigned* w = (const unsigned*)pts;
  int cnt = 0;
  for (int i = 0; i < 256; ++i) {
    unsigned e2 = (w[i] >> 7) & 0xFF;
    cnt += (e2 >= 110 && e2 <= 135);
  }
  g_flag = (cnt > 128) ? 1 : 0;
}

// ---------------- norms ----------------
template <bool XDYN>
__global__ void norms_kernel(const void* xraw, size_t xoff, int lda, int C, int BN) {
  const int isb = g_flag;
  float* norms = g_ws_f + OFF_NORMS;
  int row = blockIdx.x * (blockDim.x >> 6) + (threadIdx.x >> 6);
  int lane = threadIdx.x & 63;
  if (row >= BN) return;
  float s = 0.f;
  for (int c = lane; c < C; c += 64) {
    float v = XDYN ? ldany(xraw, (size_t)row * lda + c, isb)
                   : g_ws_f[xoff + (size_t)row * lda + c];
    s += v * v;
  }
#pragma unroll
  for (int off = 32; off > 0; off >>= 1) s += __shfl_down(s, off, 64);
  if (lane == 0) norms[row] = s;
}

// ------- split-bf16 into MFMA-fragment-tile layout -------
// out[t*512 + quad*128 + l16*8 + j], t=(r/16)*(CPAD/32)+(k/32). csh2=log2(CPAD/32).
__global__ void split_kernel(const void* xraw, size_t xoff, int lda, int C,
                             int csh2, int dst, int total) {
  int i = blockIdx.x * blockDim.x + threadIdx.x;
  if (i >= total) return;
  const int isb = g_flag;
  int t = i >> 9, win = i & 511;
  int quad = win >> 7, l16 = (win >> 3) & 15, j = win & 7;
  int ktiles_m1 = (1 << csh2) - 1;
  int rg = t >> csh2, kt = t & ktiles_m1;
  int r = rg * 16 + l16;
  int c = kt * 32 + quad * 8 + j;
  float v = 0.f;
  if (c < C)
    v = xraw ? ldany(xraw, (size_t)r * lda + c, isb) : g_ws_f[xoff + (size_t)r * lda + c];
  bf16 h = __float2bfloat16(v);
  float hf = __bfloat162float(h);
  bf16 l = __float2bfloat16(v - hf);
  unsigned short* H = dst ? g_whi : g_hi;
  unsigned short* L = dst ? g_wlo : g_lo;
  H[i] = *(unsigned short*)&h;
  L[i] = *(unsigned short*)&l;
}

// ------- fused KNN (partitioned): MFMA distances + per-partition top-10 -------
// grid (N/64, B, NPART); block 256 thr. Block scans candidates
// [part*N/NPART, ...+N/NPART), writes in-block-merged top-10 to g_pv/g_pi.
template <int CPAD>
__global__ __launch_bounds__(256) void knn_fused(int N) {
  constexpr int KT = CPAD >> 5;
  __shared__ float sd[64][67];
  __shared__ float mval[64][4][10];
  __shared__ int midx[64][4][10];
  const int tid = threadIdx.x;
  const int wave = tid >> 6, lane = tid & 63;
  const int quad = lane >> 4, l16 = lane & 15;
  const int b = blockIdx.y;
  const int q0 = blockIdx.x * 64;
  const int part = blockIdx.z;
  const int PN = N / NPART;
  const size_t rowb = (size_t)b * N;
  const float* norms = g_ws_f + OFF_NORMS;

  // A fragments held in registers (queries q0 + wave*16 + l16)
  const int arg = (int)((rowb + q0) >> 4) + wave;
  s8v ah[KT], al[KT];
#pragma unroll
  for (int kt = 0; kt < KT; ++kt) {
    const size_t abase = ((size_t)arg * KT + kt) * 512 + lane * 8;
    ah[kt] = *(const s8v*)(g_hi + abase);
    al[kt] = *(const s8v*)(g_lo + abase);
  }

  float bv[10]; int bi[10];
#pragma unroll
  for (int i = 0; i < 10; ++i) { bv[i] = FMAX; bi[i] = 0x7fffffff; }
  const int selfn = q0 + lane;  // this thread maintains query q0+lane

  for (int m0 = part * PN; m0 < (part + 1) * PN; m0 += 64) {
    f32x4 acc[4];
#pragma unroll
    for (int s = 0; s < 4; ++s) acc[s] = (f32x4){0.f, 0.f, 0.f, 0.f};
    const int brg0 = (int)((rowb + m0) >> 4);
#pragma unroll
    for (int kt = 0; kt < KT; ++kt) {
#pragma unroll
      for (int s = 0; s < 4; ++s) {
        const size_t bbase = ((size_t)(brg0 + s) * KT + kt) * 512 + lane * 8;
        s8v bh = *(const s8v*)(g_hi + bbase);
        s8v bl = *(const s8v*)(g_lo + bbase);
        acc[s] = __builtin_amdgcn_mfma_f32_16x16x32_bf16(ah[kt], bh, acc[s], 0, 0, 0);
        acc[s] = __builtin_amdgcn_mfma_f32_16x16x32_bf16(ah[kt], bl, acc[s], 0, 0, 0);
        acc[s] = __builtin_amdgcn_mfma_f32_16x16x32_bf16(al[kt], bh, acc[s], 0, 0, 0);
      }
    }
    __syncthreads();  // previous tile's scan done before overwrite
#pragma unroll
    for (int s = 0; s < 4; ++s) {
      int ml = s * 16 + l16;
      float nm = norms[rowb + m0 + ml];
#pragma unroll
      for (int r = 0; r < 4; ++r)
        sd[wave * 16 + quad * 4 + r][ml] = nm - 2.f * acc[s][r];
    }
    __syncthreads();
    // scan: thread (query=lane, slice=wave) consumes 16 candidates
    const int mbase = m0 + wave * 16;
#pragma unroll
    for (int jj = 0; jj < 16; ++jj) {
      int m = mbase + jj;
      float d = sd[lane][wave * 16 + jj];
      if (m == selfn) continue;
      bool ins = (d < bv[9]) || (d == bv[9] && m < bi[9]);
      if (ins) {
        bool prev = true;
#pragma unroll
        for (int s2 = 9; s2 >= 1; --s2) {
          bool sh = (d < bv[s2 - 1]) || (d == bv[s2 - 1] && m < bi[s2 - 1]);
          float nv = sh ? bv[s2 - 1] : (prev ? d : bv[s2]);
          int ni = sh ? bi[s2 - 1] : (prev ? m : bi[s2]);
          bv[s2] = nv; bi[s2] = ni; prev = sh;
        }
        if (prev) { bv[0] = d; bi[0] = m; }
      }
    }
  }
  // merge 4 wave-partials per query -> per-partition top-10
#pragma unroll
  for (int i = 0; i < 10; ++i) { mval[lane][wave][i] = bv[i]; midx[lane][wave][i] = bi[i]; }
  __syncthreads();
  if (tid < 64) {
    int q = tid;
    int p0 = 0, p1 = 0, p2 = 0, p3 = 0;
    size_t ob = ((rowb + q0 + q) * NPART + part) * 10;
    for (int cnt = 0; cnt < 10; ++cnt) {
      float d0 = mval[q][0][p0]; int i0 = midx[q][0][p0];
      float d1 = mval[q][1][p1]; int i1 = midx[q][1][p1];
      float d2 = mval[q][2][p2]; int i2 = midx[q][2][p2];
      float d3 = mval[q][3][p3]; int i3 = midx[q][3][p3];
      float bd = d0; int bx = i0; int bp = 0;
      if (d1 < bd || (d1 == bd && i1 < bx)) { bd = d1; bx = i1; bp = 1; }
      if (d2 < bd || (d2 == bd && i2 < bx)) { bd = d2; bx = i2; bp = 2; }
      if (d3 < bd || (d3 == bd && i3 < bx)) { bd = d3; bx = i3; bp = 3; }
      if (bp == 0) ++p0; else if (bp == 1) ++p1; else if (bp == 2) ++p2; else ++p3;
      g_pv[ob + cnt] = bd; g_pi[ob + cnt] = bx;
    }
  }
}

// ------- merge NPART sorted partial lists per query -> final top-10 -------
__global__ void knn_merge() {
  int row = blockIdx.x * blockDim.x + threadIdx.x;
  if (row >= BNTOT) return;
  const float* pv = g_pv + (size_t)row * NPART * 10;
  const int* pi = g_pi + (size_t)row * NPART * 10;
  int ptr[NPART];
#pragma unroll
  for (int p = 0; p < NPART; ++p) ptr[p] = 0;
  int* ob = g_ws_i + (size_t)row * 10;
  for (int k = 0; k < 10; ++k) {
    float bd = FMAX; int bx = 0x7fffffff; int bp = 0;
#pragma unroll
    for (int p = 0; p < NPART; ++p) {
      float d = pv[p * 10 + ptr[p]];
      int m = pi[p * 10 + ptr[p]];
      if (d < bd || (d == bd && m < bx)) { bd = d; bx = m; bp = p; }
    }
    ++ptr[bp];
    ob[k] = bx;
  }
}

// ---------------- G[z][BN][64] = X @ W_half[o_base:+64]^T ----------------
template <bool XDYN, int C>
__global__ __launch_bounds__(256) void gmat64_kernel(const void* xraw, size_t xoff,
                                                     int lda, const void* W,
                                                     int o_base, int BN) {
  const int isb = g_flag;
  constexpr int CC = (C <= 4) ? 4 : 64;
  constexpr int NCH = (C + CC - 1) / CC;
  __shared__ __align__(16) float at[CC][68];
  __shared__ __align__(16) float wt[CC][68];
  const int tid = threadIdx.x;
  const int ty = tid >> 4, tx = tid & 15;
  const int r0 = blockIdx.x * 64;
  const int z = blockIdx.z;
  float* Gz = g_ws_f + OFF_G + (size_t)z * BN * 64;
  float acc[4][4];
#pragma unroll
  for (int i = 0; i < 4; ++i)
#pragma unroll
    for (int j = 0; j < 4; ++j) acc[i][j] = 0.f;

  for (int ch = 0; ch < NCH; ++ch) {
    int c0 = ch * CC;
    for (int i = tid; i < 64 * CC; i += 256) {
      int r = i / CC, c = i % CC; int cg = c0 + c;
      size_t gi = (size_t)(r0 + r) * lda + cg;
      at[c][r] = (cg < C) ? (XDYN ? ldany(xraw, gi, isb) : g_ws_f[xoff + gi]) : 0.f;
    }
    for (int i = tid; i < 64 * CC; i += 256) {
      int r = i / CC, c = i % CC; int cg = c0 + c;
      size_t wi = (size_t)(o_base + r) * (2 * C) + (size_t)z * C + cg;
      wt[c][r] = (cg < C) ? ldany(W, wi, isb) : 0.f;
    }
    __syncthreads();
#pragma unroll 8
    for (int c = 0; c < CC; ++c) {
      const float4 a4 = *(const float4*)&at[c][4 * ty];
      const float4 w4 = *(const float4*)&wt[c][4 * tx];
      acc[0][0] += a4.x * w4.x; acc[0][1] += a4.x * w4.y; acc[0][2] += a4.x * w4.z; acc[0][3] += a4.x * w4.w;
      acc[1][0] += a4.y * w4.x; acc[1][1] += a4.y * w4.y; acc[1][2] += a4.y * w4.z; acc[1][3] += a4.y * w4.w;
      acc[2][0] += a4.z * w4.x; acc[2][1] += a4.z * w4.y; acc[2][2] += a4.z * w4.z; acc[2][3] += a4.z * w4.w;
      acc[3][0] += a4.w * w4.x; acc[3][1] += a4.w * w4.y; acc[3][2] += a4.w * w4.z; acc[3][3] += a4.w * w4.w;
    }
    __syncthreads();
  }
#pragma unroll
  for (int i = 0; i < 4; ++i)
#pragma unroll
    for (int j = 0; j < 4; ++j)
      Gz[(size_t)(r0 + 4 * ty + i) * 64 + 4 * tx + j] = acc[i][j];
}

// ---------------- edge-conv epilogue (64-out chunk) ----------------
__global__ void edge_epi64(const void* s, const void* t, int coff,
                           size_t outoff, int BN, int N) {
  const int isb = g_flag;
  int tid = threadIdx.x;
  int p = tid >> 6, o = tid & 63;
  int row = blockIdx.x * 4 + p;
  const float* G1 = g_ws_f + OFF_G;
  const float* G2 = G1 + (size_t)BN * 64;
  float* out = g_ws_f + outoff;
  int b = row / N;
  const int* id = g_ws_i + (size_t)row * 10;
  float g1n = G1[(size_t)row * 64 + o];
  float base = G2[(size_t)row * 64 + o] - g1n;
  float sv = ldany(s, coff + o, isb), tv = ldany(t, coff + o, isb);
  float mx = -FMAX;
#pragma unroll
  for (int k = 0; k < 10; ++k) {
    int m = id[k];
    m = (m < 0) ? 0 : ((m >= N) ? N - 1 : m);
    float h = sv * (G1[((size_t)b * N + m) * 64 + o] + base) + tv;
    h = (h >= 0.f) ? h : NEG * h;
    mx = fmaxf(mx, h);
  }
  out[(size_t)row * 512 + o] = mx;
}

// ------- W5 MFMA + max over n; wave tile 32n x 64o (s5>0: affine after max) ----
__global__ __launch_bounds__(256) void w5max_mfma(const void* s5, const void* t5, int N) {
  const int tid = threadIdx.x;
  const int wave = tid >> 6, lane = tid & 63;
  const int quad = lane >> 4, l16 = lane & 15;
  const int b = blockIdx.z;
  const int o0 = blockIdx.y * 64, n0 = blockIdx.x * 128;
  f32x4 acc[2][4];
#pragma unroll
  for (int a = 0; a < 2; ++a)
#pragma unroll
    for (int s = 0; s < 4; ++s) acc[a][s] = (f32x4){0.f, 0.f, 0.f, 0.f};

  const int arg0 = (int)(((size_t)b * N + n0) >> 4) + wave * 2;
  const int wrg0 = o0 >> 4;
#pragma unroll 2
  for (int kt = 0; kt < 16; ++kt) {
    s8v ah[2], al[2];
#pragma unroll
    for (int a = 0; a < 2; ++a) {
      const size_t abase = ((size_t)(arg0 + a) * 16 + kt) * 512 + lane * 8;
      ah[a] = *(const s8v*)(g_hi + abase);
      al[a] = *(const s8v*)(g_lo + abase);
    }
#pragma unroll
    for (int s = 0; s < 4; ++s) {
      const size_t bbase = ((size_t)(wrg0 + s) * 16 + kt) * 512 + lane * 8;
      s8v bh = *(const s8v*)(g_whi + bbase);
      s8v bl = *(const s8v*)(g_wlo + bbase);
#pragma unroll
      for (int a = 0; a < 2; ++a) {
        acc[a][s] = __builtin_amdgcn_mfma_f32_16x16x32_bf16(ah[a], bh, acc[a][s], 0, 0, 0);
        acc[a][s] = __builtin_amdgcn_mfma_f32_16x16x32_bf16(ah[a], bl, acc[a][s], 0, 0, 0);
        acc[a][s] = __builtin_amdgcn_mfma_f32_16x16x32_bf16(al[a], bh, acc[a][s], 0, 0, 0);
      }
    }
  }
  __shared__ float red[4][64];
  const int isb = g_flag;
#pragma unroll
  for (int s = 0; s < 4; ++s) {
    float m4 = -FMAX;
#pragma unroll
    for (int a = 0; a < 2; ++a)
#pragma unroll
      for (int r = 0; r < 4; ++r) m4 = fmaxf(m4, acc[a][s][r]);
#pragma unroll
    for (int off = 16; off < 64; off <<= 1) m4 = fmaxf(m4, __shfl_down(m4, off, 64));
    if (quad == 0) red[wave][s * 16 + l16] = m4;
  }
  __syncthreads();
  if (tid < 64) {
    float m = fmaxf(fmaxf(red[0][tid], red[1][tid]), fmaxf(red[2][tid], red[3][tid]));
    int o = o0 + tid;
    float sv = ldany(s5, o, isb), tv = ldany(t5, o, isb);
    float h = sv * m + tv;
    h = (h >= 0.f) ? h : NEG * h;
    g_ws_f[OFF_PART + ((size_t)b * 1024 + o) * 16 + blockIdx.x] = h;
  }
}

__global__ void poolred_kernel() {
  const float* part = g_ws_f + OFF_PART;
  float* pooled = g_ws_f + OFF_POOLED;
  int i = blockIdx.x * blockDim.x + threadIdx.x;
  if (i >= 8 * 1024) return;
  const float* p = part + (size_t)i * 16;
  float m = -FMAX;
#pragma unroll
  for (int j = 0; j < 16; ++j) m = fmaxf(m, p[j]);
  pooled[i] = m;
}

// ---------------- FC: one wave per output ----------------
__global__ void fc_kernel(size_t inoff, const void* W, const void* bias,
                          const void* s, const void* t, size_t outoff, int has_out,
                          void* OUTB, int Bb, int IC, int OC, int act) {
  const int isb = g_flag;
  const float* IN = g_ws_f + inoff;
  int gw = (blockIdx.x * blockDim.x + threadIdx.x) >> 6;
  int lane = threadIdx.x & 63;
  if (gw >= Bb * OC) return;
  int b = gw / OC, o = gw % OC;
  const float* in = IN + (size_t)b * IC;
  float acc = 0.f;
  for (int c = lane; c < IC; c += 64) acc += in[c] * ldany(W, (size_t)o * IC + c, isb);
#pragma unroll
  for (int off = 32; off > 0; off >>= 1) acc += __shfl_down(acc, off, 64);
  if (lane == 0) {
    float h = acc;
    if (bias) h += ldany(bias, o, isb);
    if (s) h = h * ldany(s, o, isb) + ldany(t, o, isb);
    if (act) h = (h >= 0.f) ? h : NEG * h;
    if (has_out) g_ws_f[outoff + (size_t)b * OC + o] = h;
    if (OUTB) {
      if (isb) ((bf16*)OUTB)[(size_t)b * OC + o] = __float2bfloat16(h);
      else ((float*)OUTB)[(size_t)b * OC + o] = h;
    }
  }
}

extern "C" void kernel_launch(void* const* d_in, const int* in_sizes, int n_in,
                              void* d_out, int out_size, void* d_ws, size_t ws_size,
                              hipStream_t stream) {
  const int B = 8, N = 2048, BN = B * N;
  const void* points = d_in[0];
  const void *W1 = d_in[1], *s1 = d_in[2], *t1 = d_in[3];
  const void *W2 = d_in[4], *s2 = d_in[5], *t2 = d_in[6];
  const void *W3 = d_in[7], *s3 = d_in[8], *t3 = d_in[9];
  const void *W4 = d_in[10], *s4 = d_in[11], *t4 = d_in[12];
  const void *W5 = d_in[13], *s5 = d_in[14], *t5 = d_in[15];
  const void *Wf1 = d_in[16], *sf1 = d_in[17], *tf1 = d_in[18];
  const void *Wf2 = d_in[19], *bf2 = d_in[20], *sf2 = d_in[21], *tf2 = d_in[22];
  const void *Wf3 = d_in[23], *bf3 = d_in[24];

  probe_kernel<<<1, 1, 0, stream>>>(points);
  // split W5 (1024 rows x CPAD 512, csh2=4) once
  split_kernel<<<(1024 * 512) / 256, 256, 0, stream>>>(W5, 0, 512, 512, 4, 1, 1024 * 512);

  // ---- layer 1: points (C=3, CPAD=32, csh2=0) -> cat[:, 0:64)
  norms_kernel<true><<<BN / 4, 256, 0, stream>>>(points, 0, 3, 3, BN);
  split_kernel<<<(BN * 32) / 256, 256, 0, stream>>>(points, 0, 3, 3, 0, 0, BN * 32);
  knn_fused<32><<<dim3(N / 64, B, NPART), 256, 0, stream>>>(N);
  knn_merge<<<BN / 256, 256, 0, stream>>>();
  gmat64_kernel<true, 3><<<dim3(BN / 64, 1, 2), 256, 0, stream>>>(points, 0, 3, W1, 0, BN);
  edge_epi64<<<BN / 4, 256, 0, stream>>>(s1, t1, 0, OFF_CAT + 0, BN, N);
  // ---- layer 2: cat[:,0:64) (C=64, CPAD=64, csh2=1) -> cat[:, 64:128)
  norms_kernel<false><<<BN / 4, 256, 0, stream>>>(nullptr, OFF_CAT + 0, 512, 64, BN);
  split_kernel<<<(BN * 64) / 256, 256, 0, stream>>>(nullptr, OFF_CAT + 0, 512, 64, 1, 0, BN * 64);
  knn_fused<64><<<dim3(N / 64, B, NPART), 256, 0, stream>>>(N);
  knn_merge<<<BN / 256, 256, 0, stream>>>();
  gmat64_kernel<false, 64><<<dim3(BN / 64, 1, 2), 256, 0, stream>>>(nullptr, OFF_CAT + 0, 512, W2, 0, BN);
  edge_epi64<<<BN / 4, 256, 0, stream>>>(s2, t2, 0, OFF_CAT + 64, BN, N);
  // ---- layer 3: cat[:,64:128) (C=64) -> cat[:, 128:256)
  norms_kernel<false><<<BN / 4, 256, 0, stream>>>(nullptr, OFF_CAT + 64, 512, 64, BN);
  split_kernel<<<(BN * 64) / 256, 256, 0, stream>>>(nullptr, OFF_CAT + 64, 512, 64, 1, 0, BN * 64);
  knn_fused<64><<<dim3(N / 64, B, NPART), 256, 0, stream>>>(N);
  knn_merge<<<BN / 256, 256, 0, stream>>>();
  for (int c = 0; c < 2; ++c) {
    gmat64_kernel<false, 64><<<dim3(BN / 64, 1, 2), 256, 0, stream>>>(nullptr, OFF_CAT + 64, 512, W3, c * 64, BN);
    edge_epi64<<<BN / 4, 256, 0, stream>>>(s3, t3, c * 64, OFF_CAT + 128 + c * 64, BN, N);
  }
  // ---- layer 4: cat[:,128:256) (C=128, CPAD=128, csh2=2) -> cat[:, 256:512)
  norms_kernel<false><<<BN / 4, 256, 0, stream>>>(nullptr, OFF_CAT + 128, 512, 128, BN);
  split_kernel<<<(BN * 128) / 256, 256, 0, stream>>>(nullptr, OFF_CAT + 128, 512, 128, 2, 0, BN * 128);
  knn_fused<128><<<dim3(N / 64, B, NPART), 256, 0, stream>>>(N);
  knn_merge<<<BN / 256, 256, 0, stream>>>();
  for (int c = 0; c < 4; ++c) {
    gmat64_kernel<false, 128><<<dim3(BN / 64, 1, 2), 256, 0, stream>>>(nullptr, OFF_CAT + 128, 512, W4, c * 64, BN);
    edge_epi64<<<BN / 4, 256, 0, stream>>>(s4, t4, c * 64, OFF_CAT + 256 + c * 64, BN, N);
  }
  // ---- W5 (split full cat 512 cols, csh2=4) + global max pool
  split_kernel<<<(BN * 512) / 256, 256, 0, stream>>>(nullptr, OFF_CAT, 512, 512, 4, 0, BN * 512);
  w5max_mfma<<<dim3(16, 16, 8), 256, 0, stream>>>(s5, t5, N);
  poolred_kernel<<<32, 256, 0, stream>>>();
  // ---- FC head
  fc_kernel<<<(8 * 512 * 64) / 256, 256, 0, stream>>>(OFF_POOLED, Wf1, nullptr, sf1, tf1, OFF_H1, 1, nullptr, 8, 1024, 512, 1);
  fc_kernel<<<(8 * 256 * 64) / 256, 256, 0, stream>>>(OFF_H1, Wf2, bf2, sf2, tf2, OFF_H2, 1, nullptr, 8, 512, 256, 1);
  fc_kernel<<<6, 256, 0, stream>>>(OFF_H2, Wf3, bf3, nullptr, nullptr, 0, 0, d_out, 8, 256, 3, 0);
}

// Round 11
// 866.423 us; speedup vs baseline: 1.9332x; 1.1975x over previous
//
#include <hip/hip_runtime.h>
#include <hip/hip_bf16.h>

// DGCNN-style KNN classifier. B=8, N=2048, K=10.
// g_flag=1 -> bf16 inputs, 0 -> fp32 (runtime probe). Output same dtype.
// Scratch in static __device__ globals; every byte read is written earlier in
// the same launch (graph-replay safe).
//
// R10->R11: scan overhaul. knn_fused was insert-bound (VALUBusy 53%, MfmaUtil
// 7%): 32 partial lists/query at ~90 VALU/insert. Now NPART=4 (16 lists),
// (d,idx) packed into sortable u64 (d = true sq-dist >= 0 via +qn, clamp 0;
// bits<<32 | idx -> one u64 compare = exact lexicographic order), LDS overlay
// (merge lists reuse sd pool, 20.4KB).

#define NEG 0.2f
#define FMAX 3.402823466e+38f

typedef __hip_bfloat16 bf16;
typedef __attribute__((ext_vector_type(8))) short s8v;    // 8 bf16
typedef __attribute__((ext_vector_type(4))) float f32x4;  // MFMA acc
typedef unsigned long long u64;

#define BB 8
#define NN 2048
#define BNTOT (BB * NN)
#define NPART 4

#define OFF_CAT ((size_t)0)
#define OFF_G (OFF_CAT + (size_t)BNTOT * 512)
#define OFF_NORMS (OFF_G + (size_t)BNTOT * 128)
#define OFF_PART (OFF_NORMS + BNTOT)
#define OFF_POOLED (OFF_PART + 8 * 1024 * 32)
#define OFF_H1 (OFF_POOLED + 8 * 1024)
#define OFF_H2 (OFF_H1 + 8 * 512)
#define WSF_TOTAL (OFF_H2 + 8 * 256)

__device__ float g_ws_f[WSF_TOTAL];          // ~43.1 MB
__device__ int g_ws_i[(size_t)BNTOT * 10];   // final knn idx
__device__ u64 g_pk[(size_t)BNTOT * NPART * 10];  // partial top-10 packed keys
__device__ int g_flag;                       // 1 = bf16 inputs, 0 = fp32
__device__ unsigned short g_hi[(size_t)BNTOT * 512];   // split-bf16 hi (frag-tiled)
__device__ unsigned short g_lo[(size_t)BNTOT * 512];
__device__ unsigned short g_whi[1024 * 512];           // split W5 (frag-tiled)
__device__ unsigned short g_wlo[1024 * 512];

__device__ __forceinline__ float ldany(const void* p, size_t i, int isb) {
  if (isb) return __bfloat162float(((const bf16*)p)[i]);
  return ((const float*)p)[i];
}

// ---------------- dtype probe ----------------
__global__ void probe_kernel(const void* pts) {
  const unsigned* w = (const unsigned*)pts;
  int cnt = 0;
  for (int i = 0; i < 256; ++i) {
    unsigned e2 = (w[i] >> 7) & 0xFF;
    cnt += (e2 >= 110 && e2 <= 135);
  }
  g_flag = (cnt > 128) ? 1 : 0;
}

// ---------------- norms ----------------
template <bool XDYN>
__global__ void norms_kernel(const void* xraw, size_t xoff, int lda, int C, int BN) {
  const int isb = g_flag;
  float* norms = g_ws_f + OFF_NORMS;
  int row = blockIdx.x * (blockDim.x >> 6) + (threadIdx.x >> 6);
  int lane = threadIdx.x & 63;
  if (row >= BN) return;
  float s = 0.f;
  for (int c = lane; c < C; c += 64) {
    float v = XDYN ? ldany(xraw, (size_t)row * lda + c, isb)
                   : g_ws_f[xoff + (size_t)row * lda + c];
    s += v * v;
  }
#pragma unroll
  for (int off = 32; off > 0; off >>= 1) s += __shfl_down(s, off, 64);
  if (lane == 0) norms[row] = s;
}

// ------- split-bf16 into MFMA-fragment-tile layout -------
// out[t*512 + quad*128 + l16*8 + j], t=(r/16)*(CPAD/32)+(k/32). csh2=log2(CPAD/32).
__global__ void split_kernel(const void* xraw, size_t xoff, int lda, int C,
                             int csh2, int dst, int total) {
  int i = blockIdx.x * blockDim.x + threadIdx.x;
  if (i >= total) return;
  const int isb = g_flag;
  int t = i >> 9, win = i & 511;
  int quad = win >> 7, l16 = (win >> 3) & 15, j = win & 7;
  int ktiles_m1 = (1 << csh2) - 1;
  int rg = t >> csh2, kt = t & ktiles_m1;
  int r = rg * 16 + l16;
  int c = kt * 32 + quad * 8 + j;
  float v = 0.f;
  if (c < C)
    v = xraw ? ldany(xraw, (size_t)r * lda + c, isb) : g_ws_f[xoff + (size_t)r * lda + c];
  bf16 h = __float2bfloat16(v);
  float hf = __bfloat162float(h);
  bf16 l = __float2bfloat16(v - hf);
  unsigned short* H = dst ? g_whi : g_hi;
  unsigned short* L = dst ? g_wlo : g_lo;
  H[i] = *(unsigned short*)&h;
  L[i] = *(unsigned short*)&l;
}

// ------- fused KNN (partitioned): MFMA distances + per-partition top-10 -------
// grid (N/64, B, NPART); block 256 thr. Packed-u64 selection.
template <int CPAD>
__global__ __launch_bounds__(256) void knn_fused(int N) {
  constexpr int KT = CPAD >> 5;
  __shared__ u64 spool[2560];          // 20480 B: sd[64][67] overlay + merge lists
  float* sd = (float*)spool;
  const int tid = threadIdx.x;
  const int wave = tid >> 6, lane = tid & 63;
  const int quad = lane >> 4, l16 = lane & 15;
  const int b = blockIdx.y;
  const int q0 = blockIdx.x * 64;
  const int part = blockIdx.z;
  const int PN = N / NPART;
  const size_t rowb = (size_t)b * N;
  const float* norms = g_ws_f + OFF_NORMS;

  // A fragments in registers (queries q0 + wave*16 + l16)
  const int arg = (int)((rowb + q0) >> 4) + wave;
  s8v ah[KT], al[KT];
#pragma unroll
  for (int kt = 0; kt < KT; ++kt) {
    const size_t abase = ((size_t)arg * KT + kt) * 512 + lane * 8;
    ah[kt] = *(const s8v*)(g_hi + abase);
    al[kt] = *(const s8v*)(g_lo + abase);
  }

  const int selfn = q0 + lane;       // this thread maintains query q0+lane
  const float qn = norms[rowb + selfn];
  u64 K[10];
#pragma unroll
  for (int i = 0; i < 10; ++i) K[i] = ~0ULL;

  for (int m0 = part * PN; m0 < (part + 1) * PN; m0 += 64) {
    f32x4 acc[4];
#pragma unroll
    for (int s = 0; s < 4; ++s) acc[s] = (f32x4){0.f, 0.f, 0.f, 0.f};
    const int brg0 = (int)((rowb + m0) >> 4);
#pragma unroll
    for (int kt = 0; kt < KT; ++kt) {
#pragma unroll
      for (int s = 0; s < 4; ++s) {
        const size_t bbase = ((size_t)(brg0 + s) * KT + kt) * 512 + lane * 8;
        s8v bh = *(const s8v*)(g_hi + bbase);
        s8v bl = *(const s8v*)(g_lo + bbase);
        acc[s] = __builtin_amdgcn_mfma_f32_16x16x32_bf16(ah[kt], bh, acc[s], 0, 0, 0);
        acc[s] = __builtin_amdgcn_mfma_f32_16x16x32_bf16(ah[kt], bl, acc[s], 0, 0, 0);
        acc[s] = __builtin_amdgcn_mfma_f32_16x16x32_bf16(al[kt], bh, acc[s], 0, 0, 0);
      }
    }
    __syncthreads();  // previous tile's scan done before overwrite
#pragma unroll
    for (int s = 0; s < 4; ++s) {
      int ml = s * 16 + l16;
      float nm = norms[rowb + m0 + ml];
#pragma unroll
      for (int r = 0; r < 4; ++r)
        sd[(wave * 16 + quad * 4 + r) * 67 + ml] = nm - 2.f * acc[s][r];
    }
    __syncthreads();
    // scan: thread (query=lane, slice=wave) consumes 16 candidates
    const int mbase = m0 + wave * 16;
#pragma unroll
    for (int jj = 0; jj < 16; ++jj) {
      int m = mbase + jj;
      float d = fmaxf(sd[lane * 67 + wave * 16 + jj] + qn, 0.f);
      u64 key = ((u64)__float_as_uint(d) << 32) | (unsigned)m;
      if (m == selfn) continue;
      if (key < K[9]) {
        bool prev = true;
#pragma unroll
        for (int s2 = 9; s2 >= 1; --s2) {
          bool sh = key < K[s2 - 1];
          K[s2] = sh ? K[s2 - 1] : (prev ? key : K[s2]);
          prev = sh;
        }
        if (prev) K[0] = key;
      }
    }
  }
  __syncthreads();  // sd dead; reuse spool for merge lists
#pragma unroll
  for (int i = 0; i < 10; ++i) spool[(lane * 4 + wave) * 10 + i] = K[i];
  __syncthreads();
  if (tid < 64) {
    int q = tid;
    int p0 = 0, p1 = 0, p2 = 0, p3 = 0;
    size_t ob = ((rowb + q0 + q) * NPART + part) * 10;
    for (int cnt = 0; cnt < 10; ++cnt) {
      u64 k0 = spool[(q * 4 + 0) * 10 + p0];
      u64 k1 = spool[(q * 4 + 1) * 10 + p1];
      u64 k2 = spool[(q * 4 + 2) * 10 + p2];
      u64 k3 = spool[(q * 4 + 3) * 10 + p3];
      u64 bk = k0; int bp = 0;
      if (k1 < bk) { bk = k1; bp = 1; }
      if (k2 < bk) { bk = k2; bp = 2; }
      if (k3 < bk) { bk = k3; bp = 3; }
      if (bp == 0) ++p0; else if (bp == 1) ++p1; else if (bp == 2) ++p2; else ++p3;
      g_pk[ob + cnt] = bk;
    }
  }
}

// ------- merge NPART sorted partial lists per query -> final top-10 -------
__global__ void knn_merge() {
  int row = blockIdx.x * blockDim.x + threadIdx.x;
  if (row >= BNTOT) return;
  const u64* pk = g_pk + (size_t)row * NPART * 10;
  int ptr[NPART];
#pragma unroll
  for (int p = 0; p < NPART; ++p) ptr[p] = 0;
  int* ob = g_ws_i + (size_t)row * 10;
  for (int k = 0; k < 10; ++k) {
    u64 bk = ~0ULL; int bp = 0;
#pragma unroll
    for (int p = 0; p < NPART; ++p) {
      u64 key = pk[p * 10 + ptr[p]];
      if (key < bk) { bk = key; bp = p; }
    }
    ++ptr[bp];
    ob[k] = (int)(bk & 0xFFFFFFFFu);
  }
}

// ---------------- G[z][BN][64] = X @ W_half[o_base:+64]^T ----------------
template <bool XDYN, int C>
__global__ __launch_bounds__(256) void gmat64_kernel(const void* xraw, size_t xoff,
                                                     int lda, const void* W,
                                                     int o_base, int BN) {
  const int isb = g_flag;
  constexpr int CC = (C <= 4) ? 4 : 64;
  constexpr int NCH = (C + CC - 1) / CC;
  __shared__ __align__(16) float at[CC][68];
  __shared__ __align__(16) float wt[CC][68];
  const int tid = threadIdx.x;
  const int ty = tid >> 4, tx = tid & 15;
  const int r0 = blockIdx.x * 64;
  const int z = blockIdx.z;
  float* Gz = g_ws_f + OFF_G + (size_t)z * BN * 64;
  float acc[4][4];
#pragma unroll
  for (int i = 0; i < 4; ++i)
#pragma unroll
    for (int j = 0; j < 4; ++j) acc[i][j] = 0.f;

  for (int ch = 0; ch < NCH; ++ch) {
    int c0 = ch * CC;
    for (int i = tid; i < 64 * CC; i += 256) {
      int r = i / CC, c = i % CC; int cg = c0 + c;
      size_t gi = (size_t)(r0 + r) * lda + cg;
      at[c][r] = (cg < C) ? (XDYN ? ldany(xraw, gi, isb) : g_ws_f[xoff + gi]) : 0.f;
    }
    for (int i = tid; i < 64 * CC; i += 256) {
      int r = i / CC, c = i % CC; int cg = c0 + c;
      size_t wi = (size_t)(o_base + r) * (2 * C) + (size_t)z * C + cg;
      wt[c][r] = (cg < C) ? ldany(W, wi, isb) : 0.f;
    }
    __syncthreads();
#pragma unroll 8
    for (int c = 0; c < CC; ++c) {
      const float4 a4 = *(const float4*)&at[c][4 * ty];
      const float4 w4 = *(const float4*)&wt[c][4 * tx];
      acc[0][0] += a4.x * w4.x; acc[0][1] += a4.x * w4.y; acc[0][2] += a4.x * w4.z; acc[0][3] += a4.x * w4.w;
      acc[1][0] += a4.y * w4.x; acc[1][1] += a4.y * w4.y; acc[1][2] += a4.y * w4.z; acc[1][3] += a4.y * w4.w;
      acc[2][0] += a4.z * w4.x; acc[2][1] += a4.z * w4.y; acc[2][2] += a4.z * w4.z; acc[2][3] += a4.z * w4.w;
      acc[3][0] += a4.w * w4.x; acc[3][1] += a4.w * w4.y; acc[3][2] += a4.w * w4.z; acc[3][3] += a4.w * w4.w;
    }
    __syncthreads();
  }
#pragma unroll
  for (int i = 0; i < 4; ++i)
#pragma unroll
    for (int j = 0; j < 4; ++j)
      Gz[(size_t)(r0 + 4 * ty + i) * 64 + 4 * tx + j] = acc[i][j];
}

// ---------------- edge-conv epilogue (64-out chunk) ----------------
__global__ void edge_epi64(const void* s, const void* t, int coff,
                           size_t outoff, int BN, int N) {
  const int isb = g_flag;
  int tid = threadIdx.x;
  int p = tid >> 6, o = tid & 63;
  int row = blockIdx.x * 4 + p;
  const float* G1 = g_ws_f + OFF_G;
  const float* G2 = G1 + (size_t)BN * 64;
  float* out = g_ws_f + outoff;
  int b = row / N;
  const int* id = g_ws_i + (size_t)row * 10;
  float g1n = G1[(size_t)row * 64 + o];
  float base = G2[(size_t)row * 64 + o] - g1n;
  float sv = ldany(s, coff + o, isb), tv = ldany(t, coff + o, isb);
  float mx = -FMAX;
#pragma unroll
  for (int k = 0; k < 10; ++k) {
    int m = id[k];
    m = (m < 0) ? 0 : ((m >= N) ? N - 1 : m);
    float h = sv * (G1[((size_t)b * N + m) * 64 + o] + base) + tv;
    h = (h >= 0.f) ? h : NEG * h;
    mx = fmaxf(mx, h);
  }
  out[(size_t)row * 512 + o] = mx;
}

// ------- W5 MFMA + max over n; wave tile 32n x 64o (s5>0: affine after max) ----
__global__ __launch_bounds__(256) void w5max_mfma(const void* s5, const void* t5, int N) {
  const int tid = threadIdx.x;
  const int wave = tid >> 6, lane = tid & 63;
  const int quad = lane >> 4, l16 = lane & 15;
  const int b = blockIdx.z;
  const int o0 = blockIdx.y * 64, n0 = blockIdx.x * 128;
  f32x4 acc[2][4];
#pragma unroll
  for (int a = 0; a < 2; ++a)
#pragma unroll
    for (int s = 0; s < 4; ++s) acc[a][s] = (f32x4){0.f, 0.f, 0.f, 0.f};

  const int arg0 = (int)(((size_t)b * N + n0) >> 4) + wave * 2;
  const int wrg0 = o0 >> 4;
#pragma unroll 2
  for (int kt = 0; kt < 16; ++kt) {
    s8v ah[2], al[2];
#pragma unroll
    for (int a = 0; a < 2; ++a) {
      const size_t abase = ((size_t)(arg0 + a) * 16 + kt) * 512 + lane * 8;
      ah[a] = *(const s8v*)(g_hi + abase);
      al[a] = *(const s8v*)(g_lo + abase);
    }
#pragma unroll
    for (int s = 0; s < 4; ++s) {
      const size_t bbase = ((size_t)(wrg0 + s) * 16 + kt) * 512 + lane * 8;
      s8v bh = *(const s8v*)(g_whi + bbase);
      s8v bl = *(const s8v*)(g_wlo + bbase);
#pragma unroll
      for (int a = 0; a < 2; ++a) {
        acc[a][s] = __builtin_amdgcn_mfma_f32_16x16x32_bf16(ah[a], bh, acc[a][s], 0, 0, 0);
        acc[a][s] = __builtin_amdgcn_mfma_f32_16x16x32_bf16(ah[a], bl, acc[a][s], 0, 0, 0);
        acc[a][s] = __builtin_amdgcn_mfma_f32_16x16x32_bf16(al[a], bh, acc[a][s], 0, 0, 0);
      }
    }
  }
  __shared__ float red[4][64];
  const int isb = g_flag;
#pragma unroll
  for (int s = 0; s < 4; ++s) {
    float m4 = -FMAX;
#pragma unroll
    for (int a = 0; a < 2; ++a)
#pragma unroll
      for (int r = 0; r < 4; ++r) m4 = fmaxf(m4, acc[a][s][r]);
#pragma unroll
    for (int off = 16; off < 64; off <<= 1) m4 = fmaxf(m4, __shfl_down(m4, off, 64));
    if (quad == 0) red[wave][s * 16 + l16] = m4;
  }
  __syncthreads();
  if (tid < 64) {
    float m = fmaxf(fmaxf(red[0][tid], red[1][tid]), fmaxf(red[2][tid], red[3][tid]));
    int o = o0 + tid;
    float sv = ldany(s5, o, isb), tv = ldany(t5, o, isb);
    float h = sv * m + tv;
    h = (h >= 0.f) ? h : NEG * h;
    g_ws_f[OFF_PART + ((size_t)b * 1024 + o) * 16 + blockIdx.x] = h;
  }
}

__global__ void poolred_kernel() {
  const float* part = g_ws_f + OFF_PART;
  float* pooled = g_ws_f + OFF_POOLED;
  int i = blockIdx.x * blockDim.x + threadIdx.x;
  if (i >= 8 * 1024) return;
  const float* p = part + (size_t)i * 16;
  float m = -FMAX;
#pragma unroll
  for (int j = 0; j < 16; ++j) m = fmaxf(m, p[j]);
  pooled[i] = m;
}

// ---------------- FC: one wave per output ----------------
__global__ void fc_kernel(size_t inoff, const void* W, const void* bias,
                          const void* s, const void* t, size_t outoff, int has_out,
                          void* OUTB, int Bb, int IC, int OC, int act) {
  const int isb = g_flag;
  const float* IN = g_ws_f + inoff;
  int gw = (blockIdx.x * blockDim.x + threadIdx.x) >> 6;
  int lane = threadIdx.x & 63;
  if (gw >= Bb * OC) return;
  int b = gw / OC, o = gw % OC;
  const float* in = IN + (size_t)b * IC;
  float acc = 0.f;
  for (int c = lane; c < IC; c += 64) acc += in[c] * ldany(W, (size_t)o * IC + c, isb);
#pragma unroll
  for (int off = 32; off > 0; off >>= 1) acc += __shfl_down(acc, off, 64);
  if (lane == 0) {
    float h = acc;
    if (bias) h += ldany(bias, o, isb);
    if (s) h = h * ldany(s, o, isb) + ldany(t, o, isb);
    if (act) h = (h >= 0.f) ? h : NEG * h;
    if (has_out) g_ws_f[outoff + (size_t)b * OC + o] = h;
    if (OUTB) {
      if (isb) ((bf16*)OUTB)[(size_t)b * OC + o] = __float2bfloat16(h);
      else ((float*)OUTB)[(size_t)b * OC + o] = h;
    }
  }
}

extern "C" void kernel_launch(void* const* d_in, const int* in_sizes, int n_in,
                              void* d_out, int out_size, void* d_ws, size_t ws_size,
                              hipStream_t stream) {
  const int B = 8, N = 2048, BN = B * N;
  const void* points = d_in[0];
  const void *W1 = d_in[1], *s1 = d_in[2], *t1 = d_in[3];
  const void *W2 = d_in[4], *s2 = d_in[5], *t2 = d_in[6];
  const void *W3 = d_in[7], *s3 = d_in[8], *t3 = d_in[9];
  const void *W4 = d_in[10], *s4 = d_in[11], *t4 = d_in[12];
  const void *W5 = d_in[13], *s5 = d_in[14], *t5 = d_in[15];
  const void *Wf1 = d_in[16], *sf1 = d_in[17], *tf1 = d_in[18];
  const void *Wf2 = d_in[19], *bf2 = d_in[20], *sf2 = d_in[21], *tf2 = d_in[22];
  const void *Wf3 = d_in[23], *bf3 = d_in[24];

  probe_kernel<<<1, 1, 0, stream>>>(points);
  // split W5 (1024 rows x CPAD 512, csh2=4) once
  split_kernel<<<(1024 * 512) / 256, 256, 0, stream>>>(W5, 0, 512, 512, 4, 1, 1024 * 512);

  // ---- layer 1: points (C=3, CPAD=32, csh2=0) -> cat[:, 0:64)
  norms_kernel<true><<<BN / 4, 256, 0, stream>>>(points, 0, 3, 3, BN);
  split_kernel<<<(BN * 32) / 256, 256, 0, stream>>>(points, 0, 3, 3, 0, 0, BN * 32);
  knn_fused<32><<<dim3(N / 64, B, NPART), 256, 0, stream>>>(N);
  knn_merge<<<BN / 256, 256, 0, stream>>>();
  gmat64_kernel<true, 3><<<dim3(BN / 64, 1, 2), 256, 0, stream>>>(points, 0, 3, W1, 0, BN);
  edge_epi64<<<BN / 4, 256, 0, stream>>>(s1, t1, 0, OFF_CAT + 0, BN, N);
  // ---- layer 2: cat[:,0:64) (C=64, CPAD=64, csh2=1) -> cat[:, 64:128)
  norms_kernel<false><<<BN / 4, 256, 0, stream>>>(nullptr, OFF_CAT + 0, 512, 64, BN);
  split_kernel<<<(BN * 64) / 256, 256, 0, stream>>>(nullptr, OFF_CAT + 0, 512, 64, 1, 0, BN * 64);
  knn_fused<64><<<dim3(N / 64, B, NPART), 256, 0, stream>>>(N);
  knn_merge<<<BN / 256, 256, 0, stream>>>();
  gmat64_kernel<false, 64><<<dim3(BN / 64, 1, 2), 256, 0, stream>>>(nullptr, OFF_CAT + 0, 512, W2, 0, BN);
  edge_epi64<<<BN / 4, 256, 0, stream>>>(s2, t2, 0, OFF_CAT + 64, BN, N);
  // ---- layer 3: cat[:,64:128) (C=64) -> cat[:, 128:256)
  norms_kernel<false><<<BN / 4, 256, 0, stream>>>(nullptr, OFF_CAT + 64, 512, 64, BN);
  split_kernel<<<(BN * 64) / 256, 256, 0, stream>>>(nullptr, OFF_CAT + 64, 512, 64, 1, 0, BN * 64);
  knn_fused<64><<<dim3(N / 64, B, NPART), 256, 0, stream>>>(N);
  knn_merge<<<BN / 256, 256, 0, stream>>>();
  for (int c = 0; c < 2; ++c) {
    gmat64_kernel<false, 64><<<dim3(BN / 64, 1, 2), 256, 0, stream>>>(nullptr, OFF_CAT + 64, 512, W3, c * 64, BN);
    edge_epi64<<<BN / 4, 256, 0, stream>>>(s3, t3, c * 64, OFF_CAT + 128 + c * 64, BN, N);
  }
  // ---- layer 4: cat[:,128:256) (C=128, CPAD=128, csh2=2) -> cat[:, 256:512)
  norms_kernel<false><<<BN / 4, 256, 0, stream>>>(nullptr, OFF_CAT + 128, 512, 128, BN);
  split_kernel<<<(BN * 128) / 256, 256, 0, stream>>>(nullptr, OFF_CAT + 128, 512, 128, 2, 0, BN * 128);
  knn_fused<128><<<dim3(N / 64, B, NPART), 256, 0, stream>>>(N);
  knn_merge<<<BN / 256, 256, 0, stream>>>();
  for (int c = 0; c < 4; ++c) {
    gmat64_kernel<false, 128><<<dim3(BN / 64, 1, 2), 256, 0, stream>>>(nullptr, OFF_CAT + 128, 512, W4, c * 64, BN);
    edge_epi64<<<BN / 4, 256, 0, stream>>>(s4, t4, c * 64, OFF_CAT + 256 + c * 64, BN, N);
  }
  // ---- W5 (split full cat 512 cols, csh2=4) + global max pool
  split_kernel<<<(BN * 512) / 256, 256, 0, stream>>>(nullptr, OFF_CAT, 512, 512, 4, 0, BN * 512);
  w5max_mfma<<<dim3(16, 16, 8), 256, 0, stream>>>(s5, t5, N);
  poolred_kernel<<<32, 256, 0, stream>>>();
  // ---- FC head
  fc_kernel<<<(8 * 512 * 64) / 256, 256, 0, stream>>>(OFF_POOLED, Wf1, nullptr, sf1, tf1, OFF_H1, 1, nullptr, 8, 1024, 512, 1);
  fc_kernel<<<(8 * 256 * 64) / 256, 256, 0, stream>>>(OFF_H1, Wf2, bf2, sf2, tf2, OFF_H2, 1, nullptr, 8, 512, 256, 1);
  fc_kernel<<<6, 256, 0, stream>>>(OFF_H2, Wf3, bf3, nullptr, nullptr, 0, 0, d_out, 8, 256, 3, 0);
}

// Round 12
// 703.214 us; speedup vs baseline: 2.3818x; 1.2321x over previous
//
#include <hip/hip_runtime.h>
#include <hip/hip_bf16.h>

// DGCNN-style KNN classifier. B=8, N=2048, K=10.
// g_flag=1 -> bf16 inputs, 0 -> fp32 (runtime probe). Output same dtype.
// Scratch in static __device__ globals; every byte read is written earlier in
// the same launch (graph-replay safe).
//
// R11->R12: (1) knn scan two-phase: per-tile 16-bit pass mask (cheap filter,
// uniform) then ctz-loop over passing candidates only -- wave-divergence made
// the 10-stage insert body run for ~all 128 candidates (P(any lane)~1);
// now only ~max-passes/tile (~57 total). Same keys/compares -> identical
// selection. (2) layer-3/4 gmat/epi chunk loops folded into single launches
// via g_G[chunk][z] buffer (39 -> 31 dispatches).

#define NEG 0.2f
#define FMAX 3.402823466e+38f

typedef __hip_bfloat16 bf16;
typedef __attribute__((ext_vector_type(8))) short s8v;    // 8 bf16
typedef __attribute__((ext_vector_type(4))) float f32x4;  // MFMA acc
typedef unsigned long long u64;

#define BB 8
#define NN 2048
#define BNTOT (BB * NN)
#define NPART 4

#define OFF_CAT ((size_t)0)
#define OFF_NORMS (OFF_CAT + (size_t)BNTOT * 512)
#define OFF_PART (OFF_NORMS + BNTOT)
#define OFF_POOLED (OFF_PART + 8 * 1024 * 32)
#define OFF_H1 (OFF_POOLED + 8 * 1024)
#define OFF_H2 (OFF_H1 + 8 * 512)
#define WSF_TOTAL (OFF_H2 + 8 * 256)

__device__ float g_ws_f[WSF_TOTAL];
__device__ float g_G[(size_t)8 * BNTOT * 64];     // [chunk(<=4)][z(2)][BN][64]
__device__ int g_ws_i[(size_t)BNTOT * 10];        // final knn idx
__device__ u64 g_pk[(size_t)BNTOT * NPART * 10];  // partial top-10 packed keys
__device__ int g_flag;                            // 1 = bf16 inputs, 0 = fp32
__device__ unsigned short g_hi[(size_t)BNTOT * 512];   // split-bf16 hi (frag-tiled)
__device__ unsigned short g_lo[(size_t)BNTOT * 512];
__device__ unsigned short g_whi[1024 * 512];           // split W5 (frag-tiled)
__device__ unsigned short g_wlo[1024 * 512];

__device__ __forceinline__ float ldany(const void* p, size_t i, int isb) {
  if (isb) return __bfloat162float(((const bf16*)p)[i]);
  return ((const float*)p)[i];
}

// ---------------- dtype probe ----------------
__global__ void probe_kernel(const void* pts) {
  const unsigned* w = (const unsigned*)pts;
  int cnt = 0;
  for (int i = 0; i < 256; ++i) {
    unsigned e2 = (w[i] >> 7) & 0xFF;
    cnt += (e2 >= 110 && e2 <= 135);
  }
  g_flag = (cnt > 128) ? 1 : 0;
}

// ---------------- norms ----------------
template <bool XDYN>
__global__ void norms_kernel(const void* xraw, size_t xoff, int lda, int C, int BN) {
  const int isb = g_flag;
  float* norms = g_ws_f + OFF_NORMS;
  int row = blockIdx.x * (blockDim.x >> 6) + (threadIdx.x >> 6);
  int lane = threadIdx.x & 63;
  if (row >= BN) return;
  float s = 0.f;
  for (int c = lane; c < C; c += 64) {
    float v = XDYN ? ldany(xraw, (size_t)row * lda + c, isb)
                   : g_ws_f[xoff + (size_t)row * lda + c];
    s += v * v;
  }
#pragma unroll
  for (int off = 32; off > 0; off >>= 1) s += __shfl_down(s, off, 64);
  if (lane == 0) norms[row] = s;
}

// ------- split-bf16 into MFMA-fragment-tile layout -------
__global__ void split_kernel(const void* xraw, size_t xoff, int lda, int C,
                             int csh2, int dst, int total) {
  int i = blockIdx.x * blockDim.x + threadIdx.x;
  if (i >= total) return;
  const int isb = g_flag;
  int t = i >> 9, win = i & 511;
  int quad = win >> 7, l16 = (win >> 3) & 15, j = win & 7;
  int ktiles_m1 = (1 << csh2) - 1;
  int rg = t >> csh2, kt = t & ktiles_m1;
  int r = rg * 16 + l16;
  int c = kt * 32 + quad * 8 + j;
  float v = 0.f;
  if (c < C)
    v = xraw ? ldany(xraw, (size_t)r * lda + c, isb) : g_ws_f[xoff + (size_t)r * lda + c];
  bf16 h = __float2bfloat16(v);
  float hf = __bfloat162float(h);
  bf16 l = __float2bfloat16(v - hf);
  unsigned short* H = dst ? g_whi : g_hi;
  unsigned short* L = dst ? g_wlo : g_lo;
  H[i] = *(unsigned short*)&h;
  L[i] = *(unsigned short*)&l;
}

// ------- fused KNN (partitioned): MFMA distances + per-partition top-10 -------
template <int CPAD>
__global__ __launch_bounds__(256) void knn_fused(int N) {
  constexpr int KT = CPAD >> 5;
  __shared__ u64 spool[2560];  // 20480 B: sd[64][67] overlay + merge lists
  float* sd = (float*)spool;
  const int tid = threadIdx.x;
  const int wave = tid >> 6, lane = tid & 63;
  const int quad = lane >> 4, l16 = lane & 15;
  const int b = blockIdx.y;
  const int q0 = blockIdx.x * 64;
  const int part = blockIdx.z;
  const int PN = N / NPART;
  const size_t rowb = (size_t)b * N;
  const float* norms = g_ws_f + OFF_NORMS;

  const int arg = (int)((rowb + q0) >> 4) + wave;
  s8v ah[KT], al[KT];
#pragma unroll
  for (int kt = 0; kt < KT; ++kt) {
    const size_t abase = ((size_t)arg * KT + kt) * 512 + lane * 8;
    ah[kt] = *(const s8v*)(g_hi + abase);
    al[kt] = *(const s8v*)(g_lo + abase);
  }

  const int selfn = q0 + lane;  // this thread maintains query q0+lane
  const float qn = norms[rowb + selfn];
  u64 K[10];
#pragma unroll
  for (int i = 0; i < 10; ++i) K[i] = ~0ULL;

  for (int m0 = part * PN; m0 < (part + 1) * PN; m0 += 64) {
    f32x4 acc[4];
#pragma unroll
    for (int s = 0; s < 4; ++s) acc[s] = (f32x4){0.f, 0.f, 0.f, 0.f};
    const int brg0 = (int)((rowb + m0) >> 4);
#pragma unroll
    for (int kt = 0; kt < KT; ++kt) {
#pragma unroll
      for (int s = 0; s < 4; ++s) {
        const size_t bbase = ((size_t)(brg0 + s) * KT + kt) * 512 + lane * 8;
        s8v bh = *(const s8v*)(g_hi + bbase);
        s8v bl = *(const s8v*)(g_lo + bbase);
        acc[s] = __builtin_amdgcn_mfma_f32_16x16x32_bf16(ah[kt], bh, acc[s], 0, 0, 0);
        acc[s] = __builtin_amdgcn_mfma_f32_16x16x32_bf16(ah[kt], bl, acc[s], 0, 0, 0);
        acc[s] = __builtin_amdgcn_mfma_f32_16x16x32_bf16(al[kt], bh, acc[s], 0, 0, 0);
      }
    }
    __syncthreads();  // previous tile's scan done before overwrite
#pragma unroll
    for (int s = 0; s < 4; ++s) {
      int ml = s * 16 + l16;
      float nm = norms[rowb + m0 + ml];
#pragma unroll
      for (int r = 0; r < 4; ++r)
        sd[(wave * 16 + quad * 4 + r) * 67 + ml] = nm - 2.f * acc[s][r];
    }
    __syncthreads();
    // phase 1: cheap uniform filter -> 16-bit pass mask
    const int mbase = m0 + wave * 16;
    unsigned pass = 0;
#pragma unroll
    for (int jj = 0; jj < 16; ++jj) {
      int m = mbase + jj;
      float d = fmaxf(sd[lane * 67 + wave * 16 + jj] + qn, 0.f);
      u64 key = ((u64)__float_as_uint(d) << 32) | (unsigned)m;
      bool ok = (key < K[9]) && (m != selfn);
      pass |= (unsigned)ok << jj;
    }
    // phase 2: insert only passing candidates (divergence cost = max passes)
    while (pass) {
      int jj = __builtin_ctz(pass);
      pass &= pass - 1;
      int m = mbase + jj;
      float d = fmaxf(sd[lane * 67 + wave * 16 + jj] + qn, 0.f);
      u64 key = ((u64)__float_as_uint(d) << 32) | (unsigned)m;
      if (key < K[9]) {
        bool prev = true;
#pragma unroll
        for (int s2 = 9; s2 >= 1; --s2) {
          bool sh = key < K[s2 - 1];
          K[s2] = sh ? K[s2 - 1] : (prev ? key : K[s2]);
          prev = sh;
        }
        if (prev) K[0] = key;
      }
    }
  }
  __syncthreads();  // sd dead; reuse spool for merge lists
#pragma unroll
  for (int i = 0; i < 10; ++i) spool[(lane * 4 + wave) * 10 + i] = K[i];
  __syncthreads();
  if (tid < 64) {
    int q = tid;
    int p0 = 0, p1 = 0, p2 = 0, p3 = 0;
    size_t ob = ((rowb + q0 + q) * NPART + part) * 10;
    for (int cnt = 0; cnt < 10; ++cnt) {
      u64 k0 = spool[(q * 4 + 0) * 10 + p0];
      u64 k1 = spool[(q * 4 + 1) * 10 + p1];
      u64 k2 = spool[(q * 4 + 2) * 10 + p2];
      u64 k3 = spool[(q * 4 + 3) * 10 + p3];
      u64 bk = k0; int bp = 0;
      if (k1 < bk) { bk = k1; bp = 1; }
      if (k2 < bk) { bk = k2; bp = 2; }
      if (k3 < bk) { bk = k3; bp = 3; }
      if (bp == 0) ++p0; else if (bp == 1) ++p1; else if (bp == 2) ++p2; else ++p3;
      g_pk[ob + cnt] = bk;
    }
  }
}

// ------- merge NPART sorted partial lists per query -> final top-10 -------
__global__ void knn_merge() {
  int row = blockIdx.x * blockDim.x + threadIdx.x;
  if (row >= BNTOT) return;
  const u64* pk = g_pk + (size_t)row * NPART * 10;
  int ptr[NPART];
#pragma unroll
  for (int p = 0; p < NPART; ++p) ptr[p] = 0;
  int* ob = g_ws_i + (size_t)row * 10;
  for (int k = 0; k < 10; ++k) {
    u64 bk = ~0ULL; int bp = 0;
#pragma unroll
    for (int p = 0; p < NPART; ++p) {
      u64 key = pk[p * 10 + ptr[p]];
      if (key < bk) { bk = key; bp = p; }
    }
    ++ptr[bp];
    ob[k] = (int)(bk & 0xFFFFFFFFu);
  }
}

// --- G[chunk][z][BN][64] = X @ W[o_chunk*64 ... +64][z*C ...]^T  ---
template <bool XDYN, int C>
__global__ __launch_bounds__(256) void gmat64_kernel(const void* xraw, size_t xoff,
                                                     int lda, const void* W, int BN) {
  const int isb = g_flag;
  constexpr int CC = (C <= 4) ? 4 : 64;
  constexpr int NCH = (C + CC - 1) / CC;
  __shared__ __align__(16) float at[CC][68];
  __shared__ __align__(16) float wt[CC][68];
  const int tid = threadIdx.x;
  const int ty = tid >> 4, tx = tid & 15;
  const int r0 = blockIdx.x * 64;
  const int chunk = blockIdx.y;
  const int z = blockIdx.z;
  const int o_base = chunk * 64;
  float* Gz = g_G + (size_t)(chunk * 2 + z) * BN * 64;
  float acc[4][4];
#pragma unroll
  for (int i = 0; i < 4; ++i)
#pragma unroll
    for (int j = 0; j < 4; ++j) acc[i][j] = 0.f;

  for (int ch = 0; ch < NCH; ++ch) {
    int c0 = ch * CC;
    for (int i = tid; i < 64 * CC; i += 256) {
      int r = i / CC, c = i % CC; int cg = c0 + c;
      size_t gi = (size_t)(r0 + r) * lda + cg;
      at[c][r] = (cg < C) ? (XDYN ? ldany(xraw, gi, isb) : g_ws_f[xoff + gi]) : 0.f;
    }
    for (int i = tid; i < 64 * CC; i += 256) {
      int r = i / CC, c = i % CC; int cg = c0 + c;
      size_t wi = (size_t)(o_base + r) * (2 * C) + (size_t)z * C + cg;
      wt[c][r] = (cg < C) ? ldany(W, wi, isb) : 0.f;
    }
    __syncthreads();
#pragma unroll 8
    for (int c = 0; c < CC; ++c) {
      const float4 a4 = *(const float4*)&at[c][4 * ty];
      const float4 w4 = *(const float4*)&wt[c][4 * tx];
      acc[0][0] += a4.x * w4.x; acc[0][1] += a4.x * w4.y; acc[0][2] += a4.x * w4.z; acc[0][3] += a4.x * w4.w;
      acc[1][0] += a4.y * w4.x; acc[1][1] += a4.y * w4.y; acc[1][2] += a4.y * w4.z; acc[1][3] += a4.y * w4.w;
      acc[2][0] += a4.z * w4.x; acc[2][1] += a4.z * w4.y; acc[2][2] += a4.z * w4.z; acc[2][3] += a4.z * w4.w;
      acc[3][0] += a4.w * w4.x; acc[3][1] += a4.w * w4.y; acc[3][2] += a4.w * w4.z; acc[3][3] += a4.w * w4.w;
    }
    __syncthreads();
  }
#pragma unroll
  for (int i = 0; i < 4; ++i)
#pragma unroll
    for (int j = 0; j < 4; ++j)
      Gz[(size_t)(r0 + 4 * ty + i) * 64 + 4 * tx + j] = acc[i][j];
}

// ------- edge-conv epilogue: chunk = blockIdx.y -------
__global__ void edge_epi64(const void* s, const void* t, size_t outbase,
                           int BN, int N) {
  const int isb = g_flag;
  int tid = threadIdx.x;
  int p = tid >> 6, o = tid & 63;
  int row = blockIdx.x * 4 + p;
  int chunk = blockIdx.y;
  const float* G1 = g_G + (size_t)(chunk * 2 + 0) * BN * 64;
  const float* G2 = g_G + (size_t)(chunk * 2 + 1) * BN * 64;
  float* out = g_ws_f + outbase + chunk * 64;
  int b = row / N;
  const int* id = g_ws_i + (size_t)row * 10;
  float g1n = G1[(size_t)row * 64 + o];
  float base = G2[(size_t)row * 64 + o] - g1n;
  int co = chunk * 64 + o;
  float sv = ldany(s, co, isb), tv = ldany(t, co, isb);
  float mx = -FMAX;
#pragma unroll
  for (int k = 0; k < 10; ++k) {
    int m = id[k];
    m = (m < 0) ? 0 : ((m >= N) ? N - 1 : m);
    float h = sv * (G1[((size_t)b * N + m) * 64 + o] + base) + tv;
    h = (h >= 0.f) ? h : NEG * h;
    mx = fmaxf(mx, h);
  }
  out[(size_t)row * 512 + o] = mx;
}

// ------- W5 MFMA + max over n; wave tile 32n x 64o (s5>0: affine after max) ----
__global__ __launch_bounds__(256) void w5max_mfma(const void* s5, const void* t5, int N) {
  const int tid = threadIdx.x;
  const int wave = tid >> 6, lane = tid & 63;
  const int quad = lane >> 4, l16 = lane & 15;
  const int b = blockIdx.z;
  const int o0 = blockIdx.y * 64, n0 = blockIdx.x * 128;
  f32x4 acc[2][4];
#pragma unroll
  for (int a = 0; a < 2; ++a)
#pragma unroll
    for (int s = 0; s < 4; ++s) acc[a][s] = (f32x4){0.f, 0.f, 0.f, 0.f};

  const int arg0 = (int)(((size_t)b * N + n0) >> 4) + wave * 2;
  const int wrg0 = o0 >> 4;
#pragma unroll 2
  for (int kt = 0; kt < 16; ++kt) {
    s8v ah[2], al[2];
#pragma unroll
    for (int a = 0; a < 2; ++a) {
      const size_t abase = ((size_t)(arg0 + a) * 16 + kt) * 512 + lane * 8;
      ah[a] = *(const s8v*)(g_hi + abase);
      al[a] = *(const s8v*)(g_lo + abase);
    }
#pragma unroll
    for (int s = 0; s < 4; ++s) {
      const size_t bbase = ((size_t)(wrg0 + s) * 16 + kt) * 512 + lane * 8;
      s8v bh = *(const s8v*)(g_whi + bbase);
      s8v bl = *(const s8v*)(g_wlo + bbase);
#pragma unroll
      for (int a = 0; a < 2; ++a) {
        acc[a][s] = __builtin_amdgcn_mfma_f32_16x16x32_bf16(ah[a], bh, acc[a][s], 0, 0, 0);
        acc[a][s] = __builtin_amdgcn_mfma_f32_16x16x32_bf16(ah[a], bl, acc[a][s], 0, 0, 0);
        acc[a][s] = __builtin_amdgcn_mfma_f32_16x16x32_bf16(al[a], bh, acc[a][s], 0, 0, 0);
      }
    }
  }
  __shared__ float red[4][64];
  const int isb = g_flag;
#pragma unroll
  for (int s = 0; s < 4; ++s) {
    float m4 = -FMAX;
#pragma unroll
    for (int a = 0; a < 2; ++a)
#pragma unroll
      for (int r = 0; r < 4; ++r) m4 = fmaxf(m4, acc[a][s][r]);
#pragma unroll
    for (int off = 16; off < 64; off <<= 1) m4 = fmaxf(m4, __shfl_down(m4, off, 64));
    if (quad == 0) red[wave][s * 16 + l16] = m4;
  }
  __syncthreads();
  if (tid < 64) {
    float m = fmaxf(fmaxf(red[0][tid], red[1][tid]), fmaxf(red[2][tid], red[3][tid]));
    int o = o0 + tid;
    float sv = ldany(s5, o, isb), tv = ldany(t5, o, isb);
    float h = sv * m + tv;
    h = (h >= 0.f) ? h : NEG * h;
    g_ws_f[OFF_PART + ((size_t)b * 1024 + o) * 16 + blockIdx.x] = h;
  }
}

__global__ void poolred_kernel() {
  const float* part = g_ws_f + OFF_PART;
  float* pooled = g_ws_f + OFF_POOLED;
  int i = blockIdx.x * blockDim.x + threadIdx.x;
  if (i >= 8 * 1024) return;
  const float* p = part + (size_t)i * 16;
  float m = -FMAX;
#pragma unroll
  for (int j = 0; j < 16; ++j) m = fmaxf(m, p[j]);
  pooled[i] = m;
}

// ---------------- FC: one wave per output ----------------
__global__ void fc_kernel(size_t inoff, const void* W, const void* bias,
                          const void* s, const void* t, size_t outoff, int has_out,
                          void* OUTB, int Bb, int IC, int OC, int act) {
  const int isb = g_flag;
  const float* IN = g_ws_f + inoff;
  int gw = (blockIdx.x * blockDim.x + threadIdx.x) >> 6;
  int lane = threadIdx.x & 63;
  if (gw >= Bb * OC) return;
  int b = gw / OC, o = gw % OC;
  const float* in = IN + (size_t)b * IC;
  float acc = 0.f;
  for (int c = lane; c < IC; c += 64) acc += in[c] * ldany(W, (size_t)o * IC + c, isb);
#pragma unroll
  for (int off = 32; off > 0; off >>= 1) acc += __shfl_down(acc, off, 64);
  if (lane == 0) {
    float h = acc;
    if (bias) h += ldany(bias, o, isb);
    if (s) h = h * ldany(s, o, isb) + ldany(t, o, isb);
    if (act) h = (h >= 0.f) ? h : NEG * h;
    if (has_out) g_ws_f[outoff + (size_t)b * OC + o] = h;
    if (OUTB) {
      if (isb) ((bf16*)OUTB)[(size_t)b * OC + o] = __float2bfloat16(h);
      else ((float*)OUTB)[(size_t)b * OC + o] = h;
    }
  }
}

extern "C" void kernel_launch(void* const* d_in, const int* in_sizes, int n_in,
                              void* d_out, int out_size, void* d_ws, size_t ws_size,
                              hipStream_t stream) {
  const int B = 8, N = 2048, BN = B * N;
  const void* points = d_in[0];
  const void *W1 = d_in[1], *s1 = d_in[2], *t1 = d_in[3];
  const void *W2 = d_in[4], *s2 = d_in[5], *t2 = d_in[6];
  const void *W3 = d_in[7], *s3 = d_in[8], *t3 = d_in[9];
  const void *W4 = d_in[10], *s4 = d_in[11], *t4 = d_in[12];
  const void *W5 = d_in[13], *s5 = d_in[14], *t5 = d_in[15];
  const void *Wf1 = d_in[16], *sf1 = d_in[17], *tf1 = d_in[18];
  const void *Wf2 = d_in[19], *bf2 = d_in[20], *sf2 = d_in[21], *tf2 = d_in[22];
  const void *Wf3 = d_in[23], *bf3 = d_in[24];

  probe_kernel<<<1, 1, 0, stream>>>(points);
  split_kernel<<<(1024 * 512) / 256, 256, 0, stream>>>(W5, 0, 512, 512, 4, 1, 1024 * 512);

  // ---- layer 1: points (C=3, CPAD=32) -> cat[:, 0:64)
  norms_kernel<true><<<BN / 4, 256, 0, stream>>>(points, 0, 3, 3, BN);
  split_kernel<<<(BN * 32) / 256, 256, 0, stream>>>(points, 0, 3, 3, 0, 0, BN * 32);
  knn_fused<32><<<dim3(N / 64, B, NPART), 256, 0, stream>>>(N);
  knn_merge<<<BN / 256, 256, 0, stream>>>();
  gmat64_kernel<true, 3><<<dim3(BN / 64, 1, 2), 256, 0, stream>>>(points, 0, 3, W1, BN);
  edge_epi64<<<dim3(BN / 4, 1), 256, 0, stream>>>(s1, t1, OFF_CAT + 0, BN, N);
  // ---- layer 2: cat[:,0:64) (C=64) -> cat[:, 64:128)
  norms_kernel<false><<<BN / 4, 256, 0, stream>>>(nullptr, OFF_CAT + 0, 512, 64, BN);
  split_kernel<<<(BN * 64) / 256, 256, 0, stream>>>(nullptr, OFF_CAT + 0, 512, 64, 1, 0, BN * 64);
  knn_fused<64><<<dim3(N / 64, B, NPART), 256, 0, stream>>>(N);
  knn_merge<<<BN / 256, 256, 0, stream>>>();
  gmat64_kernel<false, 64><<<dim3(BN / 64, 1, 2), 256, 0, stream>>>(nullptr, OFF_CAT + 0, 512, W2, BN);
  edge_epi64<<<dim3(BN / 4, 1), 256, 0, stream>>>(s2, t2, OFF_CAT + 64, BN, N);
  // ---- layer 3: cat[:,64:128) (C=64) -> cat[:, 128:256), 2 chunks in one go
  norms_kernel<false><<<BN / 4, 256, 0, stream>>>(nullptr, OFF_CAT + 64, 512, 64, BN);
  split_kernel<<<(BN * 64) / 256, 256, 0, stream>>>(nullptr, OFF_CAT + 64, 512, 64, 1, 0, BN * 64);
  knn_fused<64><<<dim3(N / 64, B, NPART), 256, 0, stream>>>(N);
  knn_merge<<<BN / 256, 256, 0, stream>>>();
  gmat64_kernel<false, 64><<<dim3(BN / 64, 2, 2), 256, 0, stream>>>(nullptr, OFF_CAT + 64, 512, W3, BN);
  edge_epi64<<<dim3(BN / 4, 2), 256, 0, stream>>>(s3, t3, OFF_CAT + 128, BN, N);
  // ---- layer 4: cat[:,128:256) (C=128) -> cat[:, 256:512), 4 chunks in one go
  norms_kernel<false><<<BN / 4, 256, 0, stream>>>(nullptr, OFF_CAT + 128, 512, 128, BN);
  split_kernel<<<(BN * 128) / 256, 256, 0, stream>>>(nullptr, OFF_CAT + 128, 512, 128, 2, 0, BN * 128);
  knn_fused<128><<<dim3(N / 64, B, NPART), 256, 0, stream>>>(N);
  knn_merge<<<BN / 256, 256, 0, stream>>>();
  gmat64_kernel<false, 128><<<dim3(BN / 64, 4, 2), 256, 0, stream>>>(nullptr, OFF_CAT + 128, 512, W4, BN);
  edge_epi64<<<dim3(BN / 4, 4), 256, 0, stream>>>(s4, t4, OFF_CAT + 256, BN, N);
  // ---- W5 (split full cat 512 cols) + global max pool
  split_kernel<<<(BN * 512) / 256, 256, 0, stream>>>(nullptr, OFF_CAT, 512, 512, 4, 0, BN * 512);
  w5max_mfma<<<dim3(16, 16, 8), 256, 0, stream>>>(s5, t5, N);
  poolred_kernel<<<32, 256, 0, stream>>>();
  // ---- FC head
  fc_kernel<<<(8 * 512 * 64) / 256, 256, 0, stream>>>(OFF_POOLED, Wf1, nullptr, sf1, tf1, OFF_H1, 1, nullptr, 8, 1024, 512, 1);
  fc_kernel<<<(8 * 256 * 64) / 256, 256, 0, stream>>>(OFF_H1, Wf2, bf2, sf2, tf2, OFF_H2, 1, nullptr, 8, 512, 256, 1);
  fc_kernel<<<6, 256, 0, stream>>>(OFF_H2, Wf3, bf3, nullptr, nullptr, 0, 0, d_out, 8, 256, 3, 0);
}

// Round 13
// 663.702 us; speedup vs baseline: 2.5236x; 1.0595x over previous
//
#include <hip/hip_runtime.h>
#include <hip/hip_bf16.h>

// DGCNN-style KNN classifier. B=8, N=2048, K=10.
// g_flag=1 -> bf16 inputs, 0 -> fp32 (runtime probe). Output same dtype.
// Scratch in static __device__ globals; every byte read is written earlier in
// the same launch (graph-replay safe).
//
// R12->R13: (1) gmat64 fp32 LDS-tile GEMM -> gmat_mfma reusing the layer's
// existing frag-tiled g_hi/g_lo for A; W staged into LDS frag-tiled with
// inline hi/lo split (same 3-product accuracy). (2) knn phase-1: sd stride
// 68 (16B-aligned) + float4 reads + fp32 threshold compare (ties pass, exact
// u64 recheck in phase 2 -> identical selection); FLT_MAX-bits sentinel.

#define NEG 0.2f
#define FMAX 3.402823466e+38f
#define KINIT 0x7F7FFFFFFFFFFFFFull  // (FLT_MAX bits << 32) | 0xFFFFFFFF

typedef __hip_bfloat16 bf16;
typedef __attribute__((ext_vector_type(8))) short s8v;    // 8 bf16
typedef __attribute__((ext_vector_type(4))) float f32x4;  // MFMA acc
typedef unsigned long long u64;

#define BB 8
#define NN 2048
#define BNTOT (BB * NN)
#define NPART 4

#define OFF_CAT ((size_t)0)
#define OFF_NORMS (OFF_CAT + (size_t)BNTOT * 512)
#define OFF_PART (OFF_NORMS + BNTOT)
#define OFF_POOLED (OFF_PART + 8 * 1024 * 32)
#define OFF_H1 (OFF_POOLED + 8 * 1024)
#define OFF_H2 (OFF_H1 + 8 * 512)
#define WSF_TOTAL (OFF_H2 + 8 * 256)

__device__ float g_ws_f[WSF_TOTAL];
__device__ float g_G[(size_t)8 * BNTOT * 64];     // [chunk(<=4)][z(2)][BN][64]
__device__ int g_ws_i[(size_t)BNTOT * 10];        // final knn idx
__device__ u64 g_pk[(size_t)BNTOT * NPART * 10];  // partial top-10 packed keys
__device__ int g_flag;                            // 1 = bf16 inputs, 0 = fp32
__device__ unsigned short g_hi[(size_t)BNTOT * 512];   // split-bf16 hi (frag-tiled)
__device__ unsigned short g_lo[(size_t)BNTOT * 512];
__device__ unsigned short g_whi[1024 * 512];           // split W5 (frag-tiled)
__device__ unsigned short g_wlo[1024 * 512];

__device__ __forceinline__ float ldany(const void* p, size_t i, int isb) {
  if (isb) return __bfloat162float(((const bf16*)p)[i]);
  return ((const float*)p)[i];
}

// ---------------- dtype probe ----------------
__global__ void probe_kernel(const void* pts) {
  const unsigned* w = (const unsigned*)pts;
  int cnt = 0;
  for (int i = 0; i < 256; ++i) {
    unsigned e2 = (w[i] >> 7) & 0xFF;
    cnt += (e2 >= 110 && e2 <= 135);
  }
  g_flag = (cnt > 128) ? 1 : 0;
}

// ---------------- norms ----------------
template <bool XDYN>
__global__ void norms_kernel(const void* xraw, size_t xoff, int lda, int C, int BN) {
  const int isb = g_flag;
  float* norms = g_ws_f + OFF_NORMS;
  int row = blockIdx.x * (blockDim.x >> 6) + (threadIdx.x >> 6);
  int lane = threadIdx.x & 63;
  if (row >= BN) return;
  float s = 0.f;
  for (int c = lane; c < C; c += 64) {
    float v = XDYN ? ldany(xraw, (size_t)row * lda + c, isb)
                   : g_ws_f[xoff + (size_t)row * lda + c];
    s += v * v;
  }
#pragma unroll
  for (int off = 32; off > 0; off >>= 1) s += __shfl_down(s, off, 64);
  if (lane == 0) norms[row] = s;
}

// ------- split-bf16 into MFMA-fragment-tile layout -------
__global__ void split_kernel(const void* xraw, size_t xoff, int lda, int C,
                             int csh2, int dst, int total) {
  int i = blockIdx.x * blockDim.x + threadIdx.x;
  if (i >= total) return;
  const int isb = g_flag;
  int t = i >> 9, win = i & 511;
  int quad = win >> 7, l16 = (win >> 3) & 15, j = win & 7;
  int ktiles_m1 = (1 << csh2) - 1;
  int rg = t >> csh2, kt = t & ktiles_m1;
  int r = rg * 16 + l16;
  int c = kt * 32 + quad * 8 + j;
  float v = 0.f;
  if (c < C)
    v = xraw ? ldany(xraw, (size_t)r * lda + c, isb) : g_ws_f[xoff + (size_t)r * lda + c];
  bf16 h = __float2bfloat16(v);
  float hf = __bfloat162float(h);
  bf16 l = __float2bfloat16(v - hf);
  unsigned short* H = dst ? g_whi : g_hi;
  unsigned short* L = dst ? g_wlo : g_lo;
  H[i] = *(unsigned short*)&h;
  L[i] = *(unsigned short*)&l;
}

// ------- fused KNN (partitioned): MFMA distances + per-partition top-10 -------
template <int CPAD>
__global__ __launch_bounds__(256) void knn_fused(int N) {
  constexpr int KT = CPAD >> 5;
  __shared__ u64 spool[2560];  // 20480 B: sd[64][68] (17408B) overlay + merge lists
  float* sd = (float*)spool;
  const int tid = threadIdx.x;
  const int wave = tid >> 6, lane = tid & 63;
  const int quad = lane >> 4, l16 = lane & 15;
  const int b = blockIdx.y;
  const int q0 = blockIdx.x * 64;
  const int part = blockIdx.z;
  const int PN = N / NPART;
  const size_t rowb = (size_t)b * N;
  const float* norms = g_ws_f + OFF_NORMS;

  const int arg = (int)((rowb + q0) >> 4) + wave;
  s8v ah[KT], al[KT];
#pragma unroll
  for (int kt = 0; kt < KT; ++kt) {
    const size_t abase = ((size_t)arg * KT + kt) * 512 + lane * 8;
    ah[kt] = *(const s8v*)(g_hi + abase);
    al[kt] = *(const s8v*)(g_lo + abase);
  }

  const int selfn = q0 + lane;  // this thread maintains query q0+lane
  const float qn = norms[rowb + selfn];
  u64 K[10];
#pragma unroll
  for (int i = 0; i < 10; ++i) K[i] = KINIT;

  for (int m0 = part * PN; m0 < (part + 1) * PN; m0 += 64) {
    f32x4 acc[4];
#pragma unroll
    for (int s = 0; s < 4; ++s) acc[s] = (f32x4){0.f, 0.f, 0.f, 0.f};
    const int brg0 = (int)((rowb + m0) >> 4);
#pragma unroll
    for (int kt = 0; kt < KT; ++kt) {
#pragma unroll
      for (int s = 0; s < 4; ++s) {
        const size_t bbase = ((size_t)(brg0 + s) * KT + kt) * 512 + lane * 8;
        s8v bh = *(const s8v*)(g_hi + bbase);
        s8v bl = *(const s8v*)(g_lo + bbase);
        acc[s] = __builtin_amdgcn_mfma_f32_16x16x32_bf16(ah[kt], bh, acc[s], 0, 0, 0);
        acc[s] = __builtin_amdgcn_mfma_f32_16x16x32_bf16(ah[kt], bl, acc[s], 0, 0, 0);
        acc[s] = __builtin_amdgcn_mfma_f32_16x16x32_bf16(al[kt], bh, acc[s], 0, 0, 0);
      }
    }
    __syncthreads();  // previous tile's scan done before overwrite
#pragma unroll
    for (int s = 0; s < 4; ++s) {
      int ml = s * 16 + l16;
      float nm = norms[rowb + m0 + ml];
#pragma unroll
      for (int r = 0; r < 4; ++r)
        sd[(wave * 16 + quad * 4 + r) * 68 + ml] = nm - 2.f * acc[s][r];
    }
    __syncthreads();
    // phase 1: fp32 threshold filter (ties pass; exact u64 check in phase 2)
    const int mbase = m0 + wave * 16;
    const float* srow = sd + lane * 68 + wave * 16;
    const float f9 = __uint_as_float((unsigned)(K[9] >> 32));
    unsigned pass = 0;
#pragma unroll
    for (int jj = 0; jj < 16; jj += 4) {
      float4 d4 = *(const float4*)(srow + jj);
      float d0 = fmaxf(d4.x + qn, 0.f);
      float d1 = fmaxf(d4.y + qn, 0.f);
      float d2 = fmaxf(d4.z + qn, 0.f);
      float d3 = fmaxf(d4.w + qn, 0.f);
      pass |= (unsigned)(d0 <= f9) << jj;
      pass |= (unsigned)(d1 <= f9) << (jj + 1);
      pass |= (unsigned)(d2 <= f9) << (jj + 2);
      pass |= (unsigned)(d3 <= f9) << (jj + 3);
    }
    if ((unsigned)(selfn - mbase) < 16u) pass &= ~(1u << (selfn - mbase));
    // phase 2: insert only passing candidates
    while (pass) {
      int jj = __builtin_ctz(pass);
      pass &= pass - 1;
      int m = mbase + jj;
      float d = fmaxf(srow[jj] + qn, 0.f);
      u64 key = ((u64)__float_as_uint(d) << 32) | (unsigned)m;
      if (key < K[9]) {
        bool prev = true;
#pragma unroll
        for (int s2 = 9; s2 >= 1; --s2) {
          bool sh = key < K[s2 - 1];
          K[s2] = sh ? K[s2 - 1] : (prev ? key : K[s2]);
          prev = sh;
        }
        if (prev) K[0] = key;
      }
    }
  }
  __syncthreads();  // sd dead; reuse spool for merge lists
#pragma unroll
  for (int i = 0; i < 10; ++i) spool[(lane * 4 + wave) * 10 + i] = K[i];
  __syncthreads();
  if (tid < 64) {
    int q = tid;
    int p0 = 0, p1 = 0, p2 = 0, p3 = 0;
    size_t ob = ((rowb + q0 + q) * NPART + part) * 10;
    for (int cnt = 0; cnt < 10; ++cnt) {
      u64 k0 = spool[(q * 4 + 0) * 10 + p0];
      u64 k1 = spool[(q * 4 + 1) * 10 + p1];
      u64 k2 = spool[(q * 4 + 2) * 10 + p2];
      u64 k3 = spool[(q * 4 + 3) * 10 + p3];
      u64 bk = k0; int bp = 0;
      if (k1 < bk) { bk = k1; bp = 1; }
      if (k2 < bk) { bk = k2; bp = 2; }
      if (k3 < bk) { bk = k3; bp = 3; }
      if (bp == 0) ++p0; else if (bp == 1) ++p1; else if (bp == 2) ++p2; else ++p3;
      g_pk[ob + cnt] = bk;
    }
  }
}

// ------- merge NPART sorted partial lists per query -> final top-10 -------
__global__ void knn_merge() {
  int row = blockIdx.x * blockDim.x + threadIdx.x;
  if (row >= BNTOT) return;
  const u64* pk = g_pk + (size_t)row * NPART * 10;
  int ptr[NPART];
#pragma unroll
  for (int p = 0; p < NPART; ++p) ptr[p] = 0;
  int* ob = g_ws_i + (size_t)row * 10;
  for (int k = 0; k < 10; ++k) {
    u64 bk = ~0ULL; int bp = 0;
#pragma unroll
    for (int p = 0; p < NPART; ++p) {
      u64 key = pk[p * 10 + ptr[p]];
      if (key < bk) { bk = key; bp = p; }
    }
    ++ptr[bp];
    ob[k] = (int)(bk & 0xFFFFFFFFu);
  }
}

// --- G[chunk][z] = X @ W_half^T via MFMA; A from frag-tiled g_hi/g_lo ---
template <int CPAD>
__global__ __launch_bounds__(256) void gmat_mfma(const void* W, int C, int BN) {
  constexpr int KT = CPAD >> 5;
  __shared__ __align__(16) unsigned short wbh[4 * KT * 512];
  __shared__ __align__(16) unsigned short wbl[4 * KT * 512];
  const int isb = g_flag;
  const int tid = threadIdx.x;
  const int wave = tid >> 6, lane = tid & 63;
  const int quad = lane >> 4, l16 = lane & 15;
  const int r0 = blockIdx.x * 64;
  const int chunk = blockIdx.y;
  const int z = blockIdx.z;
  const int o_base = chunk * 64;
  // stage W[o_base..+64][z*C..+C] into LDS fragment-tile (hi/lo split inline)
  for (int i = tid; i < 4 * KT * 512; i += 256) {
    int t = i >> 9, win = i & 511;
    int q2 = win >> 7, s16 = (win >> 3) & 15, j = win & 7;
    int s = t / KT, kt = t % KT;
    int orow = o_base + s * 16 + s16;
    int c = kt * 32 + q2 * 8 + j;
    float v = (c < C) ? ldany(W, (size_t)orow * (2 * C) + (size_t)z * C + c, isb) : 0.f;
    bf16 h = __float2bfloat16(v);
    float hf = __bfloat162float(h);
    bf16 l = __float2bfloat16(v - hf);
    wbh[i] = *(unsigned short*)&h;
    wbl[i] = *(unsigned short*)&l;
  }
  __syncthreads();
  f32x4 acc[4];
#pragma unroll
  for (int s = 0; s < 4; ++s) acc[s] = (f32x4){0.f, 0.f, 0.f, 0.f};
  const int arg = (r0 >> 4) + wave;
#pragma unroll
  for (int kt = 0; kt < KT; ++kt) {
    const size_t abase = ((size_t)arg * KT + kt) * 512 + lane * 8;
    s8v ah = *(const s8v*)(g_hi + abase);
    s8v al = *(const s8v*)(g_lo + abase);
#pragma unroll
    for (int s = 0; s < 4; ++s) {
      const int woff = (s * KT + kt) * 512 + lane * 8;
      s8v bh = *(const s8v*)(wbh + woff);
      s8v bl = *(const s8v*)(wbl + woff);
      acc[s] = __builtin_amdgcn_mfma_f32_16x16x32_bf16(ah, bh, acc[s], 0, 0, 0);
      acc[s] = __builtin_amdgcn_mfma_f32_16x16x32_bf16(ah, bl, acc[s], 0, 0, 0);
      acc[s] = __builtin_amdgcn_mfma_f32_16x16x32_bf16(al, bh, acc[s], 0, 0, 0);
    }
  }
  float* Gz = g_G + (size_t)(chunk * 2 + z) * BN * 64;
#pragma unroll
  for (int s = 0; s < 4; ++s)
#pragma unroll
    for (int r = 0; r < 4; ++r)
      Gz[(size_t)(r0 + wave * 16 + quad * 4 + r) * 64 + s * 16 + l16] = acc[s][r];
}

// ------- edge-conv epilogue: chunk = blockIdx.y -------
__global__ void edge_epi64(const void* s, const void* t, size_t outbase,
                           int BN, int N) {
  const int isb = g_flag;
  int tid = threadIdx.x;
  int p = tid >> 6, o = tid & 63;
  int row = blockIdx.x * 4 + p;
  int chunk = blockIdx.y;
  const float* G1 = g_G + (size_t)(chunk * 2 + 0) * BN * 64;
  const float* G2 = g_G + (size_t)(chunk * 2 + 1) * BN * 64;
  float* out = g_ws_f + outbase + chunk * 64;
  int b = row / N;
  const int* id = g_ws_i + (size_t)row * 10;
  float g1n = G1[(size_t)row * 64 + o];
  float base = G2[(size_t)row * 64 + o] - g1n;
  int co = chunk * 64 + o;
  float sv = ldany(s, co, isb), tv = ldany(t, co, isb);
  float mx = -FMAX;
#pragma unroll
  for (int k = 0; k < 10; ++k) {
    int m = id[k];
    m = (m < 0) ? 0 : ((m >= N) ? N - 1 : m);
    float h = sv * (G1[((size_t)b * N + m) * 64 + o] + base) + tv;
    h = (h >= 0.f) ? h : NEG * h;
    mx = fmaxf(mx, h);
  }
  out[(size_t)row * 512 + o] = mx;
}

// ------- W5 MFMA + max over n; wave tile 32n x 64o (s5>0: affine after max) ----
__global__ __launch_bounds__(256) void w5max_mfma(const void* s5, const void* t5, int N) {
  const int tid = threadIdx.x;
  const int wave = tid >> 6, lane = tid & 63;
  const int quad = lane >> 4, l16 = lane & 15;
  const int b = blockIdx.z;
  const int o0 = blockIdx.y * 64, n0 = blockIdx.x * 128;
  f32x4 acc[2][4];
#pragma unroll
  for (int a = 0; a < 2; ++a)
#pragma unroll
    for (int s = 0; s < 4; ++s) acc[a][s] = (f32x4){0.f, 0.f, 0.f, 0.f};

  const int arg0 = (int)(((size_t)b * N + n0) >> 4) + wave * 2;
  const int wrg0 = o0 >> 4;
#pragma unroll 2
  for (int kt = 0; kt < 16; ++kt) {
    s8v ah[2], al[2];
#pragma unroll
    for (int a = 0; a < 2; ++a) {
      const size_t abase = ((size_t)(arg0 + a) * 16 + kt) * 512 + lane * 8;
      ah[a] = *(const s8v*)(g_hi + abase);
      al[a] = *(const s8v*)(g_lo + abase);
    }
#pragma unroll
    for (int s = 0; s < 4; ++s) {
      const size_t bbase = ((size_t)(wrg0 + s) * 16 + kt) * 512 + lane * 8;
      s8v bh = *(const s8v*)(g_whi + bbase);
      s8v bl = *(const s8v*)(g_wlo + bbase);
#pragma unroll
      for (int a = 0; a < 2; ++a) {
        acc[a][s] = __builtin_amdgcn_mfma_f32_16x16x32_bf16(ah[a], bh, acc[a][s], 0, 0, 0);
        acc[a][s] = __builtin_amdgcn_mfma_f32_16x16x32_bf16(ah[a], bl, acc[a][s], 0, 0, 0);
        acc[a][s] = __builtin_amdgcn_mfma_f32_16x16x32_bf16(al[a], bh, acc[a][s], 0, 0, 0);
      }
    }
  }
  __shared__ float red[4][64];
  const int isb = g_flag;
#pragma unroll
  for (int s = 0; s < 4; ++s) {
    float m4 = -FMAX;
#pragma unroll
    for (int a = 0; a < 2; ++a)
#pragma unroll
      for (int r = 0; r < 4; ++r) m4 = fmaxf(m4, acc[a][s][r]);
#pragma unroll
    for (int off = 16; off < 64; off <<= 1) m4 = fmaxf(m4, __shfl_down(m4, off, 64));
    if (quad == 0) red[wave][s * 16 + l16] = m4;
  }
  __syncthreads();
  if (tid < 64) {
    float m = fmaxf(fmaxf(red[0][tid], red[1][tid]), fmaxf(red[2][tid], red[3][tid]));
    int o = o0 + tid;
    float sv = ldany(s5, o, isb), tv = ldany(t5, o, isb);
    float h = sv * m + tv;
    h = (h >= 0.f) ? h : NEG * h;
    g_ws_f[OFF_PART + ((size_t)b * 1024 + o) * 16 + blockIdx.x] = h;
  }
}

__global__ void poolred_kernel() {
  const float* part = g_ws_f + OFF_PART;
  float* pooled = g_ws_f + OFF_POOLED;
  int i = blockIdx.x * blockDim.x + threadIdx.x;
  if (i >= 8 * 1024) return;
  const float* p = part + (size_t)i * 16;
  float m = -FMAX;
#pragma unroll
  for (int j = 0; j < 16; ++j) m = fmaxf(m, p[j]);
  pooled[i] = m;
}

// ---------------- FC: one wave per output ----------------
__global__ void fc_kernel(size_t inoff, const void* W, const void* bias,
                          const void* s, const void* t, size_t outoff, int has_out,
                          void* OUTB, int Bb, int IC, int OC, int act) {
  const int isb = g_flag;
  const float* IN = g_ws_f + inoff;
  int gw = (blockIdx.x * blockDim.x + threadIdx.x) >> 6;
  int lane = threadIdx.x & 63;
  if (gw >= Bb * OC) return;
  int b = gw / OC, o = gw % OC;
  const float* in = IN + (size_t)b * IC;
  float acc = 0.f;
  for (int c = lane; c < IC; c += 64) acc += in[c] * ldany(W, (size_t)o * IC + c, isb);
#pragma unroll
  for (int off = 32; off > 0; off >>= 1) acc += __shfl_down(acc, off, 64);
  if (lane == 0) {
    float h = acc;
    if (bias) h += ldany(bias, o, isb);
    if (s) h = h * ldany(s, o, isb) + ldany(t, o, isb);
    if (act) h = (h >= 0.f) ? h : NEG * h;
    if (has_out) g_ws_f[outoff + (size_t)b * OC + o] = h;
    if (OUTB) {
      if (isb) ((bf16*)OUTB)[(size_t)b * OC + o] = __float2bfloat16(h);
      else ((float*)OUTB)[(size_t)b * OC + o] = h;
    }
  }
}

extern "C" void kernel_launch(void* const* d_in, const int* in_sizes, int n_in,
                              void* d_out, int out_size, void* d_ws, size_t ws_size,
                              hipStream_t stream) {
  const int B = 8, N = 2048, BN = B * N;
  const void* points = d_in[0];
  const void *W1 = d_in[1], *s1 = d_in[2], *t1 = d_in[3];
  const void *W2 = d_in[4], *s2 = d_in[5], *t2 = d_in[6];
  const void *W3 = d_in[7], *s3 = d_in[8], *t3 = d_in[9];
  const void *W4 = d_in[10], *s4 = d_in[11], *t4 = d_in[12];
  const void *W5 = d_in[13], *s5 = d_in[14], *t5 = d_in[15];
  const void *Wf1 = d_in[16], *sf1 = d_in[17], *tf1 = d_in[18];
  const void *Wf2 = d_in[19], *bf2 = d_in[20], *sf2 = d_in[21], *tf2 = d_in[22];
  const void *Wf3 = d_in[23], *bf3 = d_in[24];

  probe_kernel<<<1, 1, 0, stream>>>(points);
  split_kernel<<<(1024 * 512) / 256, 256, 0, stream>>>(W5, 0, 512, 512, 4, 1, 1024 * 512);

  // ---- layer 1: points (C=3, CPAD=32) -> cat[:, 0:64)
  norms_kernel<true><<<BN / 4, 256, 0, stream>>>(points, 0, 3, 3, BN);
  split_kernel<<<(BN * 32) / 256, 256, 0, stream>>>(points, 0, 3, 3, 0, 0, BN * 32);
  knn_fused<32><<<dim3(N / 64, B, NPART), 256, 0, stream>>>(N);
  knn_merge<<<BN / 256, 256, 0, stream>>>();
  gmat_mfma<32><<<dim3(BN / 64, 1, 2), 256, 0, stream>>>(W1, 3, BN);
  edge_epi64<<<dim3(BN / 4, 1), 256, 0, stream>>>(s1, t1, OFF_CAT + 0, BN, N);
  // ---- layer 2: cat[:,0:64) (C=64) -> cat[:, 64:128)
  norms_kernel<false><<<BN / 4, 256, 0, stream>>>(nullptr, OFF_CAT + 0, 512, 64, BN);
  split_kernel<<<(BN * 64) / 256, 256, 0, stream>>>(nullptr, OFF_CAT + 0, 512, 64, 1, 0, BN * 64);
  knn_fused<64><<<dim3(N / 64, B, NPART), 256, 0, stream>>>(N);
  knn_merge<<<BN / 256, 256, 0, stream>>>();
  gmat_mfma<64><<<dim3(BN / 64, 1, 2), 256, 0, stream>>>(W2, 64, BN);
  edge_epi64<<<dim3(BN / 4, 1), 256, 0, stream>>>(s2, t2, OFF_CAT + 64, BN, N);
  // ---- layer 3: cat[:,64:128) (C=64) -> cat[:, 128:256), 2 chunks
  norms_kernel<false><<<BN / 4, 256, 0, stream>>>(nullptr, OFF_CAT + 64, 512, 64, BN);
  split_kernel<<<(BN * 64) / 256, 256, 0, stream>>>(nullptr, OFF_CAT + 64, 512, 64, 1, 0, BN * 64);
  knn_fused<64><<<dim3(N / 64, B, NPART), 256, 0, stream>>>(N);
  knn_merge<<<BN / 256, 256, 0, stream>>>();
  gmat_mfma<64><<<dim3(BN / 64, 2, 2), 256, 0, stream>>>(W3, 64, BN);
  edge_epi64<<<dim3(BN / 4, 2), 256, 0, stream>>>(s3, t3, OFF_CAT + 128, BN, N);
  // ---- layer 4: cat[:,128:256) (C=128) -> cat[:, 256:512), 4 chunks
  norms_kernel<false><<<BN / 4, 256, 0, stream>>>(nullptr, OFF_CAT + 128, 512, 128, BN);
  split_kernel<<<(BN * 128) / 256, 256, 0, stream>>>(nullptr, OFF_CAT + 128, 512, 128, 2, 0, BN * 128);
  knn_fused<128><<<dim3(N / 64, B, NPART), 256, 0, stream>>>(N);
  knn_merge<<<BN / 256, 256, 0, stream>>>();
  gmat_mfma<128><<<dim3(BN / 64, 4, 2), 256, 0, stream>>>(W4, 128, BN);
  edge_epi64<<<dim3(BN / 4, 4), 256, 0, stream>>>(s4, t4, OFF_CAT + 256, BN, N);
  // ---- W5 (split full cat 512 cols) + global max pool
  split_kernel<<<(BN * 512) / 256, 256, 0, stream>>>(nullptr, OFF_CAT, 512, 512, 4, 0, BN * 512);
  w5max_mfma<<<dim3(16, 16, 8), 256, 0, stream>>>(s5, t5, N);
  poolred_kernel<<<32, 256, 0, stream>>>();
  // ---- FC head
  fc_kernel<<<(8 * 512 * 64) / 256, 256, 0, stream>>>(OFF_POOLED, Wf1, nullptr, sf1, tf1, OFF_H1, 1, nullptr, 8, 1024, 512, 1);
  fc_kernel<<<(8 * 256 * 64) / 256, 256, 0, stream>>>(OFF_H1, Wf2, bf2, sf2, tf2, OFF_H2, 1, nullptr, 8, 512, 256, 1);
  fc_kernel<<<6, 256, 0, stream>>>(OFF_H2, Wf3, bf3, nullptr, nullptr, 0, 0, d_out, 8, 256, 3, 0);
}

// Round 14
// 644.062 us; speedup vs baseline: 2.6006x; 1.0305x over previous
//
#include <hip/hip_runtime.h>
#include <hip/hip_bf16.h>

// DGCNN-style KNN classifier. B=8, N=2048, K=10.
// g_flag=1 -> bf16 inputs, 0 -> fp32 (runtime probe). Output same dtype.
// Scratch in static __device__ globals; every byte read is written earlier in
// the same launch (graph-replay safe).
//
// R13->R14: shared-threshold top-k. Phase-2 inserts dominated (local K[9]
// converges slowly: ~35 inserts/thread at ~50 ops). Each tile publishes each
// thread's K[9] to LDS th[wave][query]; phase-1 filters vs min over the 4
// waves (sees 4x candidates -> ~3x fewer inserts). Exact: any K[9] >= final
// global 10th-best (else 11 entries in top-10), so pruning d>T never drops a
// true member; keys/compares unchanged -> bit-identical selection.

#define NEG 0.2f
#define FMAX 3.402823466e+38f
#define KINIT 0x7F7FFFFFFFFFFFFFull  // (FLT_MAX bits << 32) | 0xFFFFFFFF

typedef __hip_bfloat16 bf16;
typedef __attribute__((ext_vector_type(8))) short s8v;    // 8 bf16
typedef __attribute__((ext_vector_type(4))) float f32x4;  // MFMA acc
typedef unsigned long long u64;

#define BB 8
#define NN 2048
#define BNTOT (BB * NN)
#define NPART 4

#define OFF_CAT ((size_t)0)
#define OFF_NORMS (OFF_CAT + (size_t)BNTOT * 512)
#define OFF_PART (OFF_NORMS + BNTOT)
#define OFF_POOLED (OFF_PART + 8 * 1024 * 32)
#define OFF_H1 (OFF_POOLED + 8 * 1024)
#define OFF_H2 (OFF_H1 + 8 * 512)
#define WSF_TOTAL (OFF_H2 + 8 * 256)

__device__ float g_ws_f[WSF_TOTAL];
__device__ float g_G[(size_t)8 * BNTOT * 64];     // [chunk(<=4)][z(2)][BN][64]
__device__ int g_ws_i[(size_t)BNTOT * 10];        // final knn idx
__device__ u64 g_pk[(size_t)BNTOT * NPART * 10];  // partial top-10 packed keys
__device__ int g_flag;                            // 1 = bf16 inputs, 0 = fp32
__device__ unsigned short g_hi[(size_t)BNTOT * 512];   // split-bf16 hi (frag-tiled)
__device__ unsigned short g_lo[(size_t)BNTOT * 512];
__device__ unsigned short g_whi[1024 * 512];           // split W5 (frag-tiled)
__device__ unsigned short g_wlo[1024 * 512];

__device__ __forceinline__ float ldany(const void* p, size_t i, int isb) {
  if (isb) return __bfloat162float(((const bf16*)p)[i]);
  return ((const float*)p)[i];
}

// ---------------- dtype probe ----------------
__global__ void probe_kernel(const void* pts) {
  const unsigned* w = (const unsigned*)pts;
  int cnt = 0;
  for (int i = 0; i < 256; ++i) {
    unsigned e2 = (w[i] >> 7) & 0xFF;
    cnt += (e2 >= 110 && e2 <= 135);
  }
  g_flag = (cnt > 128) ? 1 : 0;
}

// ---------------- norms ----------------
template <bool XDYN>
__global__ void norms_kernel(const void* xraw, size_t xoff, int lda, int C, int BN) {
  const int isb = g_flag;
  float* norms = g_ws_f + OFF_NORMS;
  int row = blockIdx.x * (blockDim.x >> 6) + (threadIdx.x >> 6);
  int lane = threadIdx.x & 63;
  if (row >= BN) return;
  float s = 0.f;
  for (int c = lane; c < C; c += 64) {
    float v = XDYN ? ldany(xraw, (size_t)row * lda + c, isb)
                   : g_ws_f[xoff + (size_t)row * lda + c];
    s += v * v;
  }
#pragma unroll
  for (int off = 32; off > 0; off >>= 1) s += __shfl_down(s, off, 64);
  if (lane == 0) norms[row] = s;
}

// ------- split-bf16 into MFMA-fragment-tile layout -------
__global__ void split_kernel(const void* xraw, size_t xoff, int lda, int C,
                             int csh2, int dst, int total) {
  int i = blockIdx.x * blockDim.x + threadIdx.x;
  if (i >= total) return;
  const int isb = g_flag;
  int t = i >> 9, win = i & 511;
  int quad = win >> 7, l16 = (win >> 3) & 15, j = win & 7;
  int ktiles_m1 = (1 << csh2) - 1;
  int rg = t >> csh2, kt = t & ktiles_m1;
  int r = rg * 16 + l16;
  int c = kt * 32 + quad * 8 + j;
  float v = 0.f;
  if (c < C)
    v = xraw ? ldany(xraw, (size_t)r * lda + c, isb) : g_ws_f[xoff + (size_t)r * lda + c];
  bf16 h = __float2bfloat16(v);
  float hf = __bfloat162float(h);
  bf16 l = __float2bfloat16(v - hf);
  unsigned short* H = dst ? g_whi : g_hi;
  unsigned short* L = dst ? g_wlo : g_lo;
  H[i] = *(unsigned short*)&h;
  L[i] = *(unsigned short*)&l;
}

// ------- fused KNN (partitioned): MFMA distances + per-partition top-10 -------
template <int CPAD>
__global__ __launch_bounds__(256) void knn_fused(int N) {
  constexpr int KT = CPAD >> 5;
  __shared__ u64 spool[2560];  // 20480 B: sd[64][68] (17408B) overlay + merge lists
  __shared__ float th[4 * 64];  // [wave][query]: each thread's current K[9] dist
  float* sd = (float*)spool;
  const int tid = threadIdx.x;
  const int wave = tid >> 6, lane = tid & 63;
  const int quad = lane >> 4, l16 = lane & 15;
  const int b = blockIdx.y;
  const int q0 = blockIdx.x * 64;
  const int part = blockIdx.z;
  const int PN = N / NPART;
  const size_t rowb = (size_t)b * N;
  const float* norms = g_ws_f + OFF_NORMS;

  const int arg = (int)((rowb + q0) >> 4) + wave;
  s8v ah[KT], al[KT];
#pragma unroll
  for (int kt = 0; kt < KT; ++kt) {
    const size_t abase = ((size_t)arg * KT + kt) * 512 + lane * 8;
    ah[kt] = *(const s8v*)(g_hi + abase);
    al[kt] = *(const s8v*)(g_lo + abase);
  }

  const int selfn = q0 + lane;  // this thread maintains query q0+lane
  const float qn = norms[rowb + selfn];
  u64 K[10];
#pragma unroll
  for (int i = 0; i < 10; ++i) K[i] = KINIT;
  th[wave * 64 + lane] = FMAX;  // covered by first in-loop barrier

  for (int m0 = part * PN; m0 < (part + 1) * PN; m0 += 64) {
    f32x4 acc[4];
#pragma unroll
    for (int s = 0; s < 4; ++s) acc[s] = (f32x4){0.f, 0.f, 0.f, 0.f};
    const int brg0 = (int)((rowb + m0) >> 4);
#pragma unroll
    for (int kt = 0; kt < KT; ++kt) {
#pragma unroll
      for (int s = 0; s < 4; ++s) {
        const size_t bbase = ((size_t)(brg0 + s) * KT + kt) * 512 + lane * 8;
        s8v bh = *(const s8v*)(g_hi + bbase);
        s8v bl = *(const s8v*)(g_lo + bbase);
        acc[s] = __builtin_amdgcn_mfma_f32_16x16x32_bf16(ah[kt], bh, acc[s], 0, 0, 0);
        acc[s] = __builtin_amdgcn_mfma_f32_16x16x32_bf16(ah[kt], bl, acc[s], 0, 0, 0);
        acc[s] = __builtin_amdgcn_mfma_f32_16x16x32_bf16(al[kt], bh, acc[s], 0, 0, 0);
      }
    }
    __syncthreads();  // previous tile's scan done before overwrite
#pragma unroll
    for (int s = 0; s < 4; ++s) {
      int ml = s * 16 + l16;
      float nm = norms[rowb + m0 + ml];
#pragma unroll
      for (int r = 0; r < 4; ++r)
        sd[(wave * 16 + quad * 4 + r) * 68 + ml] = nm - 2.f * acc[s][r];
    }
    __syncthreads();
    // shared threshold: min over 4 waves of this query's K[9] dist. Any value
    // ever in th is >= final global 10th-best, so races only tighten safely.
    const float T = fminf(fminf(th[lane], th[64 + lane]),
                          fminf(th[128 + lane], th[192 + lane]));
    // phase 1: filter d_raw + qn <= T  (fmax(x,0)<=T <=> x<=T since T>=0;
    // ties pass; exact u64 check in phase 2)
    const int mbase = m0 + wave * 16;
    const float* srow = sd + lane * 68 + wave * 16;
    unsigned pass = 0;
#pragma unroll
    for (int jj = 0; jj < 16; jj += 4) {
      float4 d4 = *(const float4*)(srow + jj);
      pass |= (unsigned)(d4.x + qn <= T) << jj;
      pass |= (unsigned)(d4.y + qn <= T) << (jj + 1);
      pass |= (unsigned)(d4.z + qn <= T) << (jj + 2);
      pass |= (unsigned)(d4.w + qn <= T) << (jj + 3);
    }
    if ((unsigned)(selfn - mbase) < 16u) pass &= ~(1u << (selfn - mbase));
    // phase 2: insert only passing candidates (exact keys)
    while (pass) {
      int jj = __builtin_ctz(pass);
      pass &= pass - 1;
      int m = mbase + jj;
      float d = fmaxf(srow[jj] + qn, 0.f);
      u64 key = ((u64)__float_as_uint(d) << 32) | (unsigned)m;
      if (key < K[9]) {
        bool prev = true;
#pragma unroll
        for (int s2 = 9; s2 >= 1; --s2) {
          bool sh = key < K[s2 - 1];
          K[s2] = sh ? K[s2 - 1] : (prev ? key : K[s2]);
          prev = sh;
        }
        if (prev) K[0] = key;
      }
    }
    th[wave * 64 + lane] = __uint_as_float((unsigned)(K[9] >> 32));
  }
  __syncthreads();  // sd dead; reuse spool for merge lists
#pragma unroll
  for (int i = 0; i < 10; ++i) spool[(lane * 4 + wave) * 10 + i] = K[i];
  __syncthreads();
  if (tid < 64) {
    int q = tid;
    int p0 = 0, p1 = 0, p2 = 0, p3 = 0;
    size_t ob = ((rowb + q0 + q) * NPART + part) * 10;
    for (int cnt = 0; cnt < 10; ++cnt) {
      u64 k0 = spool[(q * 4 + 0) * 10 + p0];
      u64 k1 = spool[(q * 4 + 1) * 10 + p1];
      u64 k2 = spool[(q * 4 + 2) * 10 + p2];
      u64 k3 = spool[(q * 4 + 3) * 10 + p3];
      u64 bk = k0; int bp = 0;
      if (k1 < bk) { bk = k1; bp = 1; }
      if (k2 < bk) { bk = k2; bp = 2; }
      if (k3 < bk) { bk = k3; bp = 3; }
      if (bp == 0) ++p0; else if (bp == 1) ++p1; else if (bp == 2) ++p2; else ++p3;
      g_pk[ob + cnt] = bk;
    }
  }
}

// ------- merge NPART sorted partial lists per query -> final top-10 -------
__global__ void knn_merge() {
  int row = blockIdx.x * blockDim.x + threadIdx.x;
  if (row >= BNTOT) return;
  const u64* pk = g_pk + (size_t)row * NPART * 10;
  int ptr[NPART];
#pragma unroll
  for (int p = 0; p < NPART; ++p) ptr[p] = 0;
  int* ob = g_ws_i + (size_t)row * 10;
  for (int k = 0; k < 10; ++k) {
    u64 bk = ~0ULL; int bp = 0;
#pragma unroll
    for (int p = 0; p < NPART; ++p) {
      u64 key = pk[p * 10 + ptr[p]];
      if (key < bk) { bk = key; bp = p; }
    }
    ++ptr[bp];
    ob[k] = (int)(bk & 0xFFFFFFFFu);
  }
}

// --- G[chunk][z] = X @ W_half^T via MFMA; A from frag-tiled g_hi/g_lo ---
template <int CPAD>
__global__ __launch_bounds__(256) void gmat_mfma(const void* W, int C, int BN) {
  constexpr int KT = CPAD >> 5;
  __shared__ __align__(16) unsigned short wbh[4 * KT * 512];
  __shared__ __align__(16) unsigned short wbl[4 * KT * 512];
  const int isb = g_flag;
  const int tid = threadIdx.x;
  const int wave = tid >> 6, lane = tid & 63;
  const int quad = lane >> 4, l16 = lane & 15;
  const int r0 = blockIdx.x * 64;
  const int chunk = blockIdx.y;
  const int z = blockIdx.z;
  const int o_base = chunk * 64;
  for (int i = tid; i < 4 * KT * 512; i += 256) {
    int t = i >> 9, win = i & 511;
    int q2 = win >> 7, s16 = (win >> 3) & 15, j = win & 7;
    int s = t / KT, kt = t % KT;
    int orow = o_base + s * 16 + s16;
    int c = kt * 32 + q2 * 8 + j;
    float v = (c < C) ? ldany(W, (size_t)orow * (2 * C) + (size_t)z * C + c, isb) : 0.f;
    bf16 h = __float2bfloat16(v);
    float hf = __bfloat162float(h);
    bf16 l = __float2bfloat16(v - hf);
    wbh[i] = *(unsigned short*)&h;
    wbl[i] = *(unsigned short*)&l;
  }
  __syncthreads();
  f32x4 acc[4];
#pragma unroll
  for (int s = 0; s < 4; ++s) acc[s] = (f32x4){0.f, 0.f, 0.f, 0.f};
  const int arg = (r0 >> 4) + wave;
#pragma unroll
  for (int kt = 0; kt < KT; ++kt) {
    const size_t abase = ((size_t)arg * KT + kt) * 512 + lane * 8;
    s8v ah = *(const s8v*)(g_hi + abase);
    s8v al = *(const s8v*)(g_lo + abase);
#pragma unroll
    for (int s = 0; s < 4; ++s) {
      const int woff = (s * KT + kt) * 512 + lane * 8;
      s8v bh = *(const s8v*)(wbh + woff);
      s8v bl = *(const s8v*)(wbl + woff);
      acc[s] = __builtin_amdgcn_mfma_f32_16x16x32_bf16(ah, bh, acc[s], 0, 0, 0);
      acc[s] = __builtin_amdgcn_mfma_f32_16x16x32_bf16(ah, bl, acc[s], 0, 0, 0);
      acc[s] = __builtin_amdgcn_mfma_f32_16x16x32_bf16(al, bh, acc[s], 0, 0, 0);
    }
  }
  float* Gz = g_G + (size_t)(chunk * 2 + z) * BN * 64;
#pragma unroll
  for (int s = 0; s < 4; ++s)
#pragma unroll
    for (int r = 0; r < 4; ++r)
      Gz[(size_t)(r0 + wave * 16 + quad * 4 + r) * 64 + s * 16 + l16] = acc[s][r];
}

// ------- edge-conv epilogue: chunk = blockIdx.y -------
__global__ void edge_epi64(const void* s, const void* t, size_t outbase,
                           int BN, int N) {
  const int isb = g_flag;
  int tid = threadIdx.x;
  int p = tid >> 6, o = tid & 63;
  int row = blockIdx.x * 4 + p;
  int chunk = blockIdx.y;
  const float* G1 = g_G + (size_t)(chunk * 2 + 0) * BN * 64;
  const float* G2 = g_G + (size_t)(chunk * 2 + 1) * BN * 64;
  float* out = g_ws_f + outbase + chunk * 64;
  int b = row / N;
  const int* id = g_ws_i + (size_t)row * 10;
  float g1n = G1[(size_t)row * 64 + o];
  float base = G2[(size_t)row * 64 + o] - g1n;
  int co = chunk * 64 + o;
  float sv = ldany(s, co, isb), tv = ldany(t, co, isb);
  float mx = -FMAX;
#pragma unroll
  for (int k = 0; k < 10; ++k) {
    int m = id[k];
    m = (m < 0) ? 0 : ((m >= N) ? N - 1 : m);
    float h = sv * (G1[((size_t)b * N + m) * 64 + o] + base) + tv;
    h = (h >= 0.f) ? h : NEG * h;
    mx = fmaxf(mx, h);
  }
  out[(size_t)row * 512 + o] = mx;
}

// ------- W5 MFMA + max over n; wave tile 32n x 64o (s5>0: affine after max) ----
__global__ __launch_bounds__(256) void w5max_mfma(const void* s5, const void* t5, int N) {
  const int tid = threadIdx.x;
  const int wave = tid >> 6, lane = tid & 63;
  const int quad = lane >> 4, l16 = lane & 15;
  const int b = blockIdx.z;
  const int o0 = blockIdx.y * 64, n0 = blockIdx.x * 128;
  f32x4 acc[2][4];
#pragma unroll
  for (int a = 0; a < 2; ++a)
#pragma unroll
    for (int s = 0; s < 4; ++s) acc[a][s] = (f32x4){0.f, 0.f, 0.f, 0.f};

  const int arg0 = (int)(((size_t)b * N + n0) >> 4) + wave * 2;
  const int wrg0 = o0 >> 4;
#pragma unroll 2
  for (int kt = 0; kt < 16; ++kt) {
    s8v ah[2], al[2];
#pragma unroll
    for (int a = 0; a < 2; ++a) {
      const size_t abase = ((size_t)(arg0 + a) * 16 + kt) * 512 + lane * 8;
      ah[a] = *(const s8v*)(g_hi + abase);
      al[a] = *(const s8v*)(g_lo + abase);
    }
#pragma unroll
    for (int s = 0; s < 4; ++s) {
      const size_t bbase = ((size_t)(wrg0 + s) * 16 + kt) * 512 + lane * 8;
      s8v bh = *(const s8v*)(g_whi + bbase);
      s8v bl = *(const s8v*)(g_wlo + bbase);
#pragma unroll
      for (int a = 0; a < 2; ++a) {
        acc[a][s] = __builtin_amdgcn_mfma_f32_16x16x32_bf16(ah[a], bh, acc[a][s], 0, 0, 0);
        acc[a][s] = __builtin_amdgcn_mfma_f32_16x16x32_bf16(ah[a], bl, acc[a][s], 0, 0, 0);
        acc[a][s] = __builtin_amdgcn_mfma_f32_16x16x32_bf16(al[a], bh, acc[a][s], 0, 0, 0);
      }
    }
  }
  __shared__ float red[4][64];
  const int isb = g_flag;
#pragma unroll
  for (int s = 0; s < 4; ++s) {
    float m4 = -FMAX;
#pragma unroll
    for (int a = 0; a < 2; ++a)
#pragma unroll
      for (int r = 0; r < 4; ++r) m4 = fmaxf(m4, acc[a][s][r]);
#pragma unroll
    for (int off = 16; off < 64; off <<= 1) m4 = fmaxf(m4, __shfl_down(m4, off, 64));
    if (quad == 0) red[wave][s * 16 + l16] = m4;
  }
  __syncthreads();
  if (tid < 64) {
    float m = fmaxf(fmaxf(red[0][tid], red[1][tid]), fmaxf(red[2][tid], red[3][tid]));
    int o = o0 + tid;
    float sv = ldany(s5, o, isb), tv = ldany(t5, o, isb);
    float h = sv * m + tv;
    h = (h >= 0.f) ? h : NEG * h;
    g_ws_f[OFF_PART + ((size_t)b * 1024 + o) * 16 + blockIdx.x] = h;
  }
}

__global__ void poolred_kernel() {
  const float* part = g_ws_f + OFF_PART;
  float* pooled = g_ws_f + OFF_POOLED;
  int i = blockIdx.x * blockDim.x + threadIdx.x;
  if (i >= 8 * 1024) return;
  const float* p = part + (size_t)i * 16;
  float m = -FMAX;
#pragma unroll
  for (int j = 0; j < 16; ++j) m = fmaxf(m, p[j]);
  pooled[i] = m;
}

// ---------------- FC: one wave per output ----------------
__global__ void fc_kernel(size_t inoff, const void* W, const void* bias,
                          const void* s, const void* t, size_t outoff, int has_out,
                          void* OUTB, int Bb, int IC, int OC, int act) {
  const int isb = g_flag;
  const float* IN = g_ws_f + inoff;
  int gw = (blockIdx.x * blockDim.x + threadIdx.x) >> 6;
  int lane = threadIdx.x & 63;
  if (gw >= Bb * OC) return;
  int b = gw / OC, o = gw % OC;
  const float* in = IN + (size_t)b * IC;
  float acc = 0.f;
  for (int c = lane; c < IC; c += 64) acc += in[c] * ldany(W, (size_t)o * IC + c, isb);
#pragma unroll
  for (int off = 32; off > 0; off >>= 1) acc += __shfl_down(acc, off, 64);
  if (lane == 0) {
    float h = acc;
    if (bias) h += ldany(bias, o, isb);
    if (s) h = h * ldany(s, o, isb) + ldany(t, o, isb);
    if (act) h = (h >= 0.f) ? h : NEG * h;
    if (has_out) g_ws_f[outoff + (size_t)b * OC + o] = h;
    if (OUTB) {
      if (isb) ((bf16*)OUTB)[(size_t)b * OC + o] = __float2bfloat16(h);
      else ((float*)OUTB)[(size_t)b * OC + o] = h;
    }
  }
}

extern "C" void kernel_launch(void* const* d_in, const int* in_sizes, int n_in,
                              void* d_out, int out_size, void* d_ws, size_t ws_size,
                              hipStream_t stream) {
  const int B = 8, N = 2048, BN = B * N;
  const void* points = d_in[0];
  const void *W1 = d_in[1], *s1 = d_in[2], *t1 = d_in[3];
  const void *W2 = d_in[4], *s2 = d_in[5], *t2 = d_in[6];
  const void *W3 = d_in[7], *s3 = d_in[8], *t3 = d_in[9];
  const void *W4 = d_in[10], *s4 = d_in[11], *t4 = d_in[12];
  const void *W5 = d_in[13], *s5 = d_in[14], *t5 = d_in[15];
  const void *Wf1 = d_in[16], *sf1 = d_in[17], *tf1 = d_in[18];
  const void *Wf2 = d_in[19], *bf2 = d_in[20], *sf2 = d_in[21], *tf2 = d_in[22];
  const void *Wf3 = d_in[23], *bf3 = d_in[24];

  probe_kernel<<<1, 1, 0, stream>>>(points);
  split_kernel<<<(1024 * 512) / 256, 256, 0, stream>>>(W5, 0, 512, 512, 4, 1, 1024 * 512);

  // ---- layer 1: points (C=3, CPAD=32) -> cat[:, 0:64)
  norms_kernel<true><<<BN / 4, 256, 0, stream>>>(points, 0, 3, 3, BN);
  split_kernel<<<(BN * 32) / 256, 256, 0, stream>>>(points, 0, 3, 3, 0, 0, BN * 32);
  knn_fused<32><<<dim3(N / 64, B, NPART), 256, 0, stream>>>(N);
  knn_merge<<<BN / 256, 256, 0, stream>>>();
  gmat_mfma<32><<<dim3(BN / 64, 1, 2), 256, 0, stream>>>(W1, 3, BN);
  edge_epi64<<<dim3(BN / 4, 1), 256, 0, stream>>>(s1, t1, OFF_CAT + 0, BN, N);
  // ---- layer 2: cat[:,0:64) (C=64) -> cat[:, 64:128)
  norms_kernel<false><<<BN / 4, 256, 0, stream>>>(nullptr, OFF_CAT + 0, 512, 64, BN);
  split_kernel<<<(BN * 64) / 256, 256, 0, stream>>>(nullptr, OFF_CAT + 0, 512, 64, 1, 0, BN * 64);
  knn_fused<64><<<dim3(N / 64, B, NPART), 256, 0, stream>>>(N);
  knn_merge<<<BN / 256, 256, 0, stream>>>();
  gmat_mfma<64><<<dim3(BN / 64, 1, 2), 256, 0, stream>>>(W2, 64, BN);
  edge_epi64<<<dim3(BN / 4, 1), 256, 0, stream>>>(s2, t2, OFF_CAT + 64, BN, N);
  // ---- layer 3: cat[:,64:128) (C=64) -> cat[:, 128:256), 2 chunks
  norms_kernel<false><<<BN / 4, 256, 0, stream>>>(nullptr, OFF_CAT + 64, 512, 64, BN);
  split_kernel<<<(BN * 64) / 256, 256, 0, stream>>>(nullptr, OFF_CAT + 64, 512, 64, 1, 0, BN * 64);
  knn_fused<64><<<dim3(N / 64, B, NPART), 256, 0, stream>>>(N);
  knn_merge<<<BN / 256, 256, 0, stream>>>();
  gmat_mfma<64><<<dim3(BN / 64, 2, 2), 256, 0, stream>>>(W3, 64, BN);
  edge_epi64<<<dim3(BN / 4, 2), 256, 0, stream>>>(s3, t3, OFF_CAT + 128, BN, N);
  // ---- layer 4: cat[:,128:256) (C=128) -> cat[:, 256:512), 4 chunks
  norms_kernel<false><<<BN / 4, 256, 0, stream>>>(nullptr, OFF_CAT + 128, 512, 128, BN);
  split_kernel<<<(BN * 128) / 256, 256, 0, stream>>>(nullptr, OFF_CAT + 128, 512, 128, 2, 0, BN * 128);
  knn_fused<128><<<dim3(N / 64, B, NPART), 256, 0, stream>>>(N);
  knn_merge<<<BN / 256, 256, 0, stream>>>();
  gmat_mfma<128><<<dim3(BN / 64, 4, 2), 256, 0, stream>>>(W4, 128, BN);
  edge_epi64<<<dim3(BN / 4, 4), 256, 0, stream>>>(s4, t4, OFF_CAT + 256, BN, N);
  // ---- W5 (split full cat 512 cols) + global max pool
  split_kernel<<<(BN * 512) / 256, 256, 0, stream>>>(nullptr, OFF_CAT, 512, 512, 4, 0, BN * 512);
  w5max_mfma<<<dim3(16, 16, 8), 256, 0, stream>>>(s5, t5, N);
  poolred_kernel<<<32, 256, 0, stream>>>();
  // ---- FC head
  fc_kernel<<<(8 * 512 * 64) / 256, 256, 0, stream>>>(OFF_POOLED, Wf1, nullptr, sf1, tf1, OFF_H1, 1, nullptr, 8, 1024, 512, 1);
  fc_kernel<<<(8 * 256 * 64) / 256, 256, 0, stream>>>(OFF_H1, Wf2, bf2, sf2, tf2, OFF_H2, 1, nullptr, 8, 512, 256, 1);
  fc_kernel<<<6, 256, 0, stream>>>(OFF_H2, Wf3, bf3, nullptr, nullptr, 0, 0, d_out, 8, 256, 3, 0);
}